// Round 4
// baseline (8305.610 us; speedup 1.0000x reference)
//
#include <hip/hip_runtime.h>

typedef unsigned short u16;
typedef unsigned int u32;
typedef unsigned long long u64;
typedef __attribute__((ext_vector_type(8))) short bf16x8;
typedef __attribute__((ext_vector_type(4))) float f32x4;

__device__ __forceinline__ float b2f(u16 x) {
  union { u32 u; float f; } c; c.u = ((u32)x) << 16; return c.f;
}
__device__ __forceinline__ u16 f2b(float f) {
  union { float f; u32 u; } c; c.f = f;
  u32 u = c.u;
  return (u16)((u + 0x7FFFu + ((u >> 16) & 1u)) >> 16);
}
__device__ __forceinline__ float sigf(float x) { return 1.f / (1.f + __expf(-x)); }
__device__ __forceinline__ float tanhfast(float x) {
  float e = __expf(2.f * x);
  return 1.f - 2.f / (e + 1.f);
}
__device__ __forceinline__ float clampf(float x, float b) {
  return fminf(fmaxf(x, -b), b);
}
__device__ __forceinline__ float loadin(const void* p, long i, u32 isf32) {
  return isf32 ? ((const float*)p)[i] : b2f(((const u16*)p)[i]);
}
// L2-bypassing coherent read (straight from coherence point)
__device__ __forceinline__ u32 l3_load(const u32* p) {
  u32 v;
  asm volatile("global_load_dword %0, %1, off sc0 sc1\n\ts_waitcnt vmcnt(0)"
               : "=v"(v) : "v"(p) : "memory");
  return v;
}
// Two coherent reads with a single latency exposure (pipelined, one drain).
__device__ __forceinline__ void l3_load2(const u32* p0, const u32* p1,
                                         u32& v0, u32& v1) {
  asm volatile("global_load_dword %0, %2, off sc0 sc1\n\t"
               "global_load_dword %1, %3, off sc0 sc1\n\t"
               "s_waitcnt vmcnt(0)"
               : "=v"(v0), "=v"(v1) : "v"(p0), "v"(p1) : "memory");
}
// Write-through store (never lingers dirty in local L2)
__device__ __forceinline__ void l3_store(u32* p, u32 v) {
  asm volatile("global_store_dword %0, %1, off sc0 sc1" :: "v"(p), "v"(v) : "memory");
}
__device__ __forceinline__ void vm_drain() {
  asm volatile("s_waitcnt vmcnt(0)" ::: "memory");
}

// Layouts:
//  hsT[t][w8][b][j]  u16 idx = t*32768 + w8*512 + b*8 + j   (w8=64 col-octets)
//  xT [s][k8][b][j]  u16 idx = s*20480 + k8*512 + b*8 + j   (k8=40 col-octets)
// For 16x16x32 MFMA, lane (lrow=lane&15, kq=lane>>4) of wave wv (batch rows
// wv*16..wv*16+15) reads its A-frag at u16 idx (ks*4+kq)*512 + (wv*16+lrow)*8
// -> 16B contiguous in global; A goes straight to registers, no LDS staging.

// ---------------------------------------------------------------------------
__global__ __launch_bounds__(256) void detect_kernel(const u16* __restrict__ bih0,
                                                     u32* __restrict__ flag) {
  __shared__ u32 cnts[2];
  if (threadIdx.x < 2) cnts[threadIdx.x] = 0;
  __syncthreads();
  u32 huge = 0, zeros = 0;
  for (int i = threadIdx.x; i < 2048; i += 256) {
    u16 v = bih0[i];
    u32 e = (v >> 7) & 0xFFu;
    if (e >= 0xC0u) huge++;
    if (v == 0) zeros++;
  }
  atomicAdd(&cnts[0], huge);
  atomicAdd(&cnts[1], zeros);
  __syncthreads();
  if (threadIdx.x == 0) flag[0] = (cnts[0] >= 8u || cnts[1] >= 600u) ? 1u : 0u;
}

// ---------------------------------------------------------------------------
__global__ __launch_bounds__(256) void prep_kernel(
    const void* __restrict__ Wih0, const void* __restrict__ Whh0,
    const void* __restrict__ bih0, const void* __restrict__ bhh0,
    const void* __restrict__ Wih1, const void* __restrict__ Whh1,
    const void* __restrict__ bih1, const void* __restrict__ bhh1,
    const void* __restrict__ W1, const void* __restrict__ b1,
    const void* __restrict__ W2, const void* __restrict__ b2,
    const void* __restrict__ Wf, const void* __restrict__ bfv,
    u16* __restrict__ Wcat0, u16* __restrict__ Wcat1,
    float* __restrict__ biasR0, float* __restrict__ biasR1,
    u16* __restrict__ W1c, float* __restrict__ b1c,
    float* __restrict__ W2c, float* __restrict__ b2c,
    float* __restrict__ Wfc, float* __restrict__ bfc,
    const u32* __restrict__ flag)
{
  const u32 isf32 = flag[0];
  const int gid = blockIdx.x * 256 + threadIdx.x;
  const int gsz = gridDim.x * 256;
  for (int i = gid; i < 2048 * 832; i += gsz) {
    int np = i / 832, k = i - np * 832;
    int g = np & 3, j = np >> 2;
    long orig = g * 512 + j;
    u16 v;
    if (k < 320) v = (k < 300) ? f2b(loadin(Wih0, orig * 300 + k, isf32)) : (u16)0;
    else         v = f2b(loadin(Whh0, orig * 512 + (k - 320), isf32));
    Wcat0[i] = v;
  }
  for (int i = gid; i < 2048 * 1024; i += gsz) {
    int np = i >> 10, k = i & 1023;
    int g = np & 3, j = np >> 2;
    long orig = g * 512 + j;
    Wcat1[i] = (k < 512) ? f2b(loadin(Wih1, orig * 512 + k, isf32))
                         : f2b(loadin(Whh1, orig * 512 + (k - 512), isf32));
  }
  for (int i = gid; i < 2048; i += gsz) {
    int g = i & 3, j = i >> 2;
    long orig = g * 512 + j;
    biasR0[i] = loadin(bih0, orig, isf32) + loadin(bhh0, orig, isf32);
    biasR1[i] = loadin(bih1, orig, isf32) + loadin(bhh1, orig, isf32);
  }
  for (int i = gid; i < 256 * 1024; i += gsz) W1c[i] = f2b(loadin(W1, i, isf32));
  for (int i = gid; i < 256; i += gsz) {
    b1c[i] = loadin(b1, i, isf32);
    W2c[i] = loadin(W2, i, isf32);
  }
  for (int i = gid; i < 1024; i += gsz) Wfc[i] = loadin(Wf, i, isf32);
  if (gid == 0) {
    b2c[0] = loadin(b2, 0, isf32);
    bfc[0] = loadin(bfv, 0, isf32);
  }
}

// ---------------------------------------------------------------------------
// gather -> xT layout: xT[s][c>>3][b][c&7]
// ---------------------------------------------------------------------------
__global__ __launch_bounds__(256) void gather_kernel(
    const int* __restrict__ xi, const void* __restrict__ embed,
    u16* __restrict__ xT, const u32* __restrict__ flag)
{
  const u32 isf32 = flag[0];
  const int r = blockIdx.x * 4 + (threadIdx.x >> 6);
  const int lane = threadIdx.x & 63;
  const int b = r & 63, s = r >> 6;
  const int idx = xi[b * 1024 + s];
  u16* dst = xT + (u64)s * 20480 + b * 8;
  if (!isf32) {
    const u16* src = (const u16*)embed + (u64)idx * 300;
    for (int c = lane; c < 300; c += 64) dst[(c >> 3) * 512 + (c & 7)] = src[c];
  } else {
    const float* src = (const float*)embed + (u64)idx * 300;
    for (int c = lane; c < 300; c += 64) dst[(c >> 3) * 512 + (c & 7)] = f2b(src[c]);
  }
  for (int c = 300 + lane; c < 320; c += 64) dst[(c >> 3) * 512 + (c & 7)] = 0;
}

// ---------------------------------------------------------------------------
// Fused persistent 2-layer LSTM. 128 WGs: 0-63 layer0, 64-127 layer1 (lag 1).
// Round-0 skeleton (batch-split waves, full-K per wave, weights in LDS,
// 64 parallel flag lines) with three chain segments removed:
//  - A-fragments load straight to registers (no LDS tile, no stage barriers)
//  - layer-1 polls cross+own flags in ONE combined poll (one discovery)
//  - layer-0 pre-issues its x-fragment loads before the wait
// Two __syncthreads per step (z exchange; store drain before flag post).
// ---------------------------------------------------------------------------
__global__ __launch_bounds__(256, 1) void lstm_fused(
    const u16* __restrict__ xT,
    const u16* __restrict__ Wcat0, const float* __restrict__ biasR0,
    const u16* __restrict__ Wcat1, const float* __restrict__ biasR1,
    u16* __restrict__ h0sT, u16* __restrict__ h1sT,
    u32* __restrict__ flags0, u32* __restrict__ flags1, int S)
{
  __shared__ __align__(16) u16 ldsW[32 * 1032];   // weight slice, padded pitch
  __shared__ float ldsZ[64 * 33];

  const int layer = blockIdx.x >> 6;
  const int w = blockIdx.x & 63;
  const int KX = layer ? 512 : 320;
  const u16* Wcat = layer ? Wcat1 : Wcat0;
  const float* biasR = layer ? biasR1 : biasR0;
  u16* hs = layer ? h1sT : h0sT;
  u32* fown = layer ? flags1 : flags0;

  const int tid = threadIdx.x;
  const int lane = tid & 63;
  const int wv = tid >> 6;
  const int Kt = KX + 512;
  const int PW = Kt + 8;
  const int nu32 = Kt >> 1;

  {   // weight slice rows w*32..w*32+31 -> LDS (one-time)
    const u32* src = (const u32*)Wcat;
    u32* dst = (u32*)ldsW;
    const int pw2 = PW >> 1;
    for (int i = tid; i < 32 * nu32; i += 256) {
      int r = i / nu32, c = i - r * nu32;
      dst[r * pw2 + c] = src[(u64)(w * 32 + r) * nu32 + c];
    }
  }
  __syncthreads();

  const int nksX = KX >> 5;                 // 10 or 16
  const int lrow = lane & 15;
  const int kq = lane >> 4;
  const u64 arow = (u64)(wv * 16 + lrow) * 8;   // A-frag row offset (u16)
  const int gb = tid >> 2;                  // gates: batch row
  const int gj0 = (tid & 3) * 2;            // gates: first h-col pair
  float c0 = 0.f, c1 = 0.f;                 // c-state, register-resident

  for (int t = 0; t < S; ++t) {
    f32x4 acc0 = {0.f, 0.f, 0.f, 0.f};
    f32x4 acc1 = {0.f, 0.f, 0.f, 0.f};
    bf16x8 ax[16];

    if (layer == 0) {
      // pre-issue x-frag loads (independent of any flag) -> overlap the wait
      const u16* xp = xT + (u64)t * 20480 + (u64)kq * 512 + arow;
#pragma unroll
      for (int i = 0; i < 10; ++i) ax[i] = *(const bf16x8*)(xp + (u64)i * 2048);
      if (t > 0) {
        if (wv == 0) {
          const u32* fp = flags0 + lane * 16;
          const u32 tgt = (u32)t;
          while (!__all((int)(l3_load(fp) >= tgt))) __builtin_amdgcn_s_sleep(1);
        }
        __syncthreads();
      }
    } else {
      // combined cross+own wait: one discovery period covers both
      if (wv == 0) {
        const u32* fpc = flags0 + lane * 16;
        const u32* fpo = flags1 + lane * 16;
        const u32 tgtc = (u32)(t + 1), tgto = (u32)t;
        for (;;) {
          u32 vc, vo;
          if (t > 0) l3_load2(fpc, fpo, vc, vo);
          else { vc = l3_load(fpc); vo = tgto; }
          if (__all((int)((vc >= tgtc) && (vo >= tgto)))) break;
          __builtin_amdgcn_s_sleep(1);
        }
      }
      __syncthreads();
      const u16* xp = h0sT + (u64)t * 32768 + (u64)kq * 512 + arow;
#pragma unroll
      for (int i = 0; i < 16; ++i) ax[i] = *(const bf16x8*)(xp + (u64)i * 2048);
    }

    // recurrent A-frags (own-layer h(t-1)); issued together with ax -> one
    // latency exposure for the whole step's A data
    bf16x8 ah[16];
    if (t > 0) {
      const u16* hp = hs + (u64)(t - 1) * 32768 + (u64)kq * 512 + arow;
#pragma unroll
      for (int i = 0; i < 16; ++i) ah[i] = *(const bf16x8*)(hp + (u64)i * 2048);
    }

    // x/h0 projection MFMAs
    for (int ks = 0; ks < nksX; ++ks) {
      int k = ks * 32 + kq * 8;
      bf16x8 b0 = *(const bf16x8*)&ldsW[lrow * PW + k];
      bf16x8 b1 = *(const bf16x8*)&ldsW[(16 + lrow) * PW + k];
      acc0 = __builtin_amdgcn_mfma_f32_16x16x32_bf16(ax[ks], b0, acc0, 0, 0, 0);
      acc1 = __builtin_amdgcn_mfma_f32_16x16x32_bf16(ax[ks], b1, acc1, 0, 0, 0);
    }
    // recurrent MFMAs
    if (t > 0) {
      for (int ks = 0; ks < 16; ++ks) {
        int k = KX + ks * 32 + kq * 8;
        bf16x8 b0 = *(const bf16x8*)&ldsW[lrow * PW + k];
        bf16x8 b1 = *(const bf16x8*)&ldsW[(16 + lrow) * PW + k];
        acc0 = __builtin_amdgcn_mfma_f32_16x16x32_bf16(ah[ks], b0, acc0, 0, 0, 0);
        acc1 = __builtin_amdgcn_mfma_f32_16x16x32_bf16(ah[ks], b1, acc1, 0, 0, 0);
      }
    }

    // z tile -> LDS (C layout: col=lane&15, row=quad*4+reg)
    {
      int col = lane & 15, q = lane >> 4;
#pragma unroll
      for (int r = 0; r < 4; ++r) {
        int m = wv * 16 + q * 4 + r;
        ldsZ[m * 33 + col] = acc0[r];
        ldsZ[m * 33 + 16 + col] = acc1[r];
      }
    }
    __syncthreads();

    // gates + contiguous full-line h store
    {
      float hv[2];
#pragma unroll
      for (int q2 = 0; q2 < 2; ++q2) {
        int cb = (gj0 + q2) * 4;
        float zi = clampf(ldsZ[gb * 33 + cb + 0] + biasR[w * 32 + cb + 0], 30.f);
        float zf = clampf(ldsZ[gb * 33 + cb + 1] + biasR[w * 32 + cb + 1], 30.f);
        float zg = clampf(ldsZ[gb * 33 + cb + 2] + biasR[w * 32 + cb + 2], 30.f);
        float zo = clampf(ldsZ[gb * 33 + cb + 3] + biasR[w * 32 + cb + 3], 30.f);
        float co = q2 ? c1 : c0;
        float cn = clampf(sigf(zf) * co + sigf(zi) * tanhfast(zg), 64.f);
        if (q2) c1 = cn; else c0 = cn;
        hv[q2] = clampf(sigf(zo) * tanhfast(cn), 1.f);
      }
      u32 packed = (u32)f2b(hv[0]) | ((u32)f2b(hv[1]) << 16);
      l3_store((u32*)hs + (u64)t * 16384 + w * 256 + tid, packed);
      vm_drain();
    }
    __syncthreads();            // all threads' h stores at coherence point
    if (tid == 0) l3_store(fown + w * 16, (u32)(t + 1));
  }
}

// ---------------------------------------------------------------------------
// gemm over hsT A: C[M=65536,N=256](bf16) = A_hsT @ B[N,K=512]^T. 128x128.
// ---------------------------------------------------------------------------
__global__ __launch_bounds__(256, 1) void gemm_hA(
    const u16* __restrict__ A,
    const u16* __restrict__ B, int ldb,
    u16* __restrict__ C, int ldc, int K)
{
  __shared__ __align__(16) u16 As[128 * 40];
  __shared__ __align__(16) u16 Bs[128 * 40];
  const int tid = threadIdx.x;
  const int bn = blockIdx.x * 128;
  const int bm = blockIdx.y * 128;
  const int lane = tid & 63;
  const int wv = tid >> 6;
  const int mh = wv >> 1, nh = wv & 1;
  const int lrow = lane & 15, kq = lane >> 4;
  const int sr = tid >> 1, sh = (tid & 1) * 16;
  const int m_ = bm + sr, s_ = m_ >> 6, bb = m_ & 63;
  f32x4 acc[4][4];
#pragma unroll
  for (int i = 0; i < 4; ++i)
#pragma unroll
    for (int j = 0; j < 4; ++j) acc[i][j] = {0.f, 0.f, 0.f, 0.f};

  for (int k0 = 0; k0 < K; k0 += 32) {
    const u16* ap = A + (u64)s_ * 32768 + (u64)((k0 + sh) >> 3) * 512 + bb * 8;
    *(bf16x8*)&As[sr * 40 + sh]     = *(const bf16x8*)ap;
    *(bf16x8*)&As[sr * 40 + sh + 8] = *(const bf16x8*)(ap + 512);
    *(bf16x8*)&Bs[sr * 40 + sh]     = *(const bf16x8*)(B + (u64)(bn + sr) * ldb + k0 + sh);
    *(bf16x8*)&Bs[sr * 40 + sh + 8] = *(const bf16x8*)(B + (u64)(bn + sr) * ldb + k0 + sh + 8);
    __syncthreads();
    bf16x8 af[4], bfr[4];
#pragma unroll
    for (int mt = 0; mt < 4; ++mt)
      af[mt] = *(const bf16x8*)&As[(mh * 64 + mt * 16 + lrow) * 40 + kq * 8];
#pragma unroll
    for (int nt = 0; nt < 4; ++nt)
      bfr[nt] = *(const bf16x8*)&Bs[(nh * 64 + nt * 16 + lrow) * 40 + kq * 8];
#pragma unroll
    for (int mt = 0; mt < 4; ++mt)
#pragma unroll
      for (int nt = 0; nt < 4; ++nt)
        acc[mt][nt] = __builtin_amdgcn_mfma_f32_16x16x32_bf16(af[mt], bfr[nt], acc[mt][nt], 0, 0, 0);
    __syncthreads();
  }
#pragma unroll
  for (int mt = 0; mt < 4; ++mt)
#pragma unroll
    for (int nt = 0; nt < 4; ++nt)
#pragma unroll
      for (int r = 0; r < 4; ++r) {
        int m = bm + mh * 64 + mt * 16 + kq * 4 + r;
        int n = bn + nh * 64 + nt * 16 + lrow;
        C[(u64)m * ldc + n] = f2b(clampf(acc[mt][nt][r], 60.f));
      }
}

// ---------------------------------------------------------------------------
__global__ __launch_bounds__(256) void part1_kernel(
    const u16* __restrict__ h1sT, const u16* __restrict__ W1c,
    const float* __restrict__ b1c, float* __restrict__ part1)
{
  __shared__ float hN[512];
  const int b = blockIdx.x;
  const int l = threadIdx.x;
  for (int i = l; i < 512; i += 256)
    hN[i] = b2f(h1sT[(u64)1023 * 32768 + (i >> 3) * 512 + b * 8 + (i & 7)]);
  __syncthreads();
  const u16* wrow = W1c + (u64)l * 1024;
  float acc = b1c[l];
  for (int k = 0; k < 512; ++k) acc += hN[k] * b2f(wrow[k]);
  part1[b * 256 + l] = clampf(acc, 60.f);
}

// ---------------------------------------------------------------------------
__global__ __launch_bounds__(256) void escore_kernel(
    const float* __restrict__ part1, const u16* __restrict__ part2,
    const float* __restrict__ W2c, const float* __restrict__ b2c,
    float* __restrict__ e)
{
  const int m = blockIdx.x * 4 + (threadIdx.x >> 6);
  const int lane = threadIdx.x & 63;
  const int b = m & 63, s = m >> 6;
  float acc = 0.f;
  for (int l = lane; l < 256; l += 64)
    acc += tanhfast(part1[b * 256 + l] + b2f(part2[(u64)m * 256 + l])) * W2c[l];
#pragma unroll
  for (int off = 32; off; off >>= 1) acc += __shfl_down(acc, off, 64);
  if (lane == 0) e[b * 1024 + s] = clampf(acc + b2c[0], 60.f);
}

// ---------------------------------------------------------------------------
__global__ __launch_bounds__(256) void finish_kernel(
    const float* __restrict__ e, const u16* __restrict__ h1sT,
    const float* __restrict__ Wfc, const float* __restrict__ bfc,
    void* __restrict__ dout, const u32* __restrict__ flag)
{
  __shared__ float sw[1024];
  __shared__ float red[4];
  __shared__ float hN[512];
  const u32 isf32 = flag[0];
  const int b = blockIdx.x;
  const int tid = threadIdx.x;
  const int lane = tid & 63, wv = tid >> 6;

  float mx = -1e30f;
  for (int s = tid; s < 1024; s += 256) {
    float v = e[b * 1024 + s];
    sw[s] = v;
    mx = fmaxf(mx, v);
  }
#pragma unroll
  for (int off = 1; off < 64; off <<= 1) mx = fmaxf(mx, __shfl_xor(mx, off, 64));
  if (lane == 0) red[wv] = mx;
  __syncthreads();
  mx = fmaxf(fmaxf(red[0], red[1]), fmaxf(red[2], red[3]));
  __syncthreads();

  float sum = 0.f;
  for (int s = tid; s < 1024; s += 256) {
    float p = __expf(sw[s] - mx);
    sw[s] = p;
    sum += p;
  }
#pragma unroll
  for (int off = 1; off < 64; off <<= 1) sum += __shfl_xor(sum, off, 64);
  if (lane == 0) red[wv] = sum;
  __syncthreads();
  sum = red[0] + red[1] + red[2] + red[3];
  float inv = 1.f / sum;
  for (int s = tid; s < 1024; s += 256) {
    float wn = sw[s] * inv;
    sw[s] = wn;
    if (isf32) ((float*)dout)[b * 1024 + s] = wn;
    else       ((u16*)dout)[b * 1024 + s] = f2b(wn);
  }
  for (int i = tid; i < 512; i += 256)
    hN[i] = b2f(h1sT[(u64)1023 * 32768 + (i >> 3) * 512 + b * 8 + (i & 7)]);
  __syncthreads();

  const int c0 = tid, c1 = tid + 256;
  const u64 off0 = (u64)(c0 >> 3) * 512 + b * 8 + (c0 & 7);
  const u64 off1 = (u64)(c1 >> 3) * 512 + b * 8 + (c1 & 7);
  float a0 = 0.f, a1 = 0.f;
  for (int s = 0; s < 1024; ++s) {
    const u16* hr = h1sT + (u64)s * 32768;
    float wn = sw[s];
    a0 += wn * b2f(hr[off0]);
    a1 += wn * b2f(hr[off1]);
  }
  float part = a0 * Wfc[c0] + a1 * Wfc[c1] + hN[c0] * Wfc[512 + c0] + hN[c1] * Wfc[512 + c1];
#pragma unroll
  for (int off = 1; off < 64; off <<= 1) part += __shfl_xor(part, off, 64);
  __syncthreads();
  if (lane == 0) red[wv] = part;
  __syncthreads();
  if (tid == 0) {
    float tot = clampf(red[0] + red[1] + red[2] + red[3] + bfc[0], 30.f);
    float o = sigf(tot);
    if (isf32) ((float*)dout)[65536 + b] = o;
    else       ((u16*)dout)[65536 + b] = f2b(o);
  }
}

// ---------------------------------------------------------------------------
extern "C" void kernel_launch(void* const* d_in, const int* in_sizes, int n_in,
                              void* d_out, int out_size, void* d_ws, size_t ws_size,
                              hipStream_t stream) {
  const int* x_index = (const int*)d_in[0];
  const void* embed = d_in[1];
  const void* Wih0 = d_in[2];
  const void* Whh0 = d_in[3];
  const void* bih0 = d_in[4];
  const void* bhh0 = d_in[5];
  const void* Wih1 = d_in[6];
  const void* Whh1 = d_in[7];
  const void* bih1 = d_in[8];
  const void* bhh1 = d_in[9];
  const void* W1 = d_in[10];
  const void* b1 = d_in[11];
  const void* W2 = d_in[12];
  const void* b2 = d_in[13];
  const void* Wf = d_in[14];
  const void* bfv = d_in[15];

  char* ws = (char*)d_ws;
  size_t off = 0;
  auto alloc = [&](size_t bytes) -> char* {
    char* p = ws + off;
    off += (bytes + 255) & ~(size_t)255;
    return p;
  };
  u32* flags0    = (u32*)alloc(64 * 16 * 4);   // one flag per 64B line
  u32* flags1    = (u32*)alloc(64 * 16 * 4);
  u32* flag      = (u32*)alloc(256);
  float* biasR0  = (float*)alloc(2048 * 4);
  float* biasR1  = (float*)alloc(2048 * 4);
  float* part1   = (float*)alloc(64 * 256 * 4);
  float* e       = (float*)alloc(64 * 1024 * 4);
  float* b1c     = (float*)alloc(256 * 4);
  float* W2c     = (float*)alloc(256 * 4);
  float* b2c     = (float*)alloc(16);
  float* Wfc     = (float*)alloc(1024 * 4);
  float* bfc     = (float*)alloc(16);
  u16* W1c       = (u16*)alloc((size_t)256 * 1024 * 2);
  u16* Wcat0     = (u16*)alloc((size_t)2048 * 832 * 2);
  u16* Wcat1     = (u16*)alloc((size_t)2048 * 1024 * 2);
  u16* xT        = (u16*)alloc((size_t)65536 * 320 * 2);
  u16* h0sT      = (u16*)alloc((size_t)65536 * 512 * 2);
  u16* h1sT      = (u16*)alloc((size_t)65536 * 512 * 2);
  u16* part2     = (u16*)alloc((size_t)65536 * 256 * 2);
  (void)ws_size; (void)in_sizes; (void)n_in; (void)out_size;

  hipMemsetAsync(flags0, 0, 64 * 16 * 4 * 2, stream);  // flags0 + flags1
  hipLaunchKernelGGL(detect_kernel, dim3(1), dim3(256), 0, stream,
                     (const u16*)bih0, flag);
  hipLaunchKernelGGL(prep_kernel, dim3(512), dim3(256), 0, stream,
                     Wih0, Whh0, bih0, bhh0, Wih1, Whh1, bih1, bhh1,
                     W1, b1, W2, b2, Wf, bfv,
                     Wcat0, Wcat1, biasR0, biasR1,
                     W1c, b1c, W2c, b2c, Wfc, bfc, flag);
  hipLaunchKernelGGL(gather_kernel, dim3(16384), dim3(256), 0, stream,
                     x_index, embed, xT, flag);
  hipLaunchKernelGGL(lstm_fused, dim3(128), dim3(256), 0, stream,
                     xT, Wcat0, biasR0, Wcat1, biasR1,
                     h0sT, h1sT, flags0, flags1, 1024);
  hipLaunchKernelGGL(part1_kernel, dim3(64), dim3(256), 0, stream,
                     h1sT, W1c, b1c, part1);
  hipLaunchKernelGGL(gemm_hA, dim3(2, 512), dim3(256), 0, stream,
                     h1sT, W1c + 512, 1024, part2, 256, 512);
  hipLaunchKernelGGL(escore_kernel, dim3(16384), dim3(256), 0, stream,
                     part1, part2, W2c, b2c, e);
  hipLaunchKernelGGL(finish_kernel, dim3(64), dim3(256), 0, stream,
                     e, h1sT, Wfc, bfc, d_out, flag);
}

// Round 6
// 6391.565 us; speedup vs baseline: 1.2995x; 1.2995x over previous
//
#include <hip/hip_runtime.h>

typedef unsigned short u16;
typedef unsigned int u32;
typedef unsigned long long u64;
typedef __attribute__((ext_vector_type(8))) short bf16x8;
typedef __attribute__((ext_vector_type(4))) float f32x4;

__device__ __forceinline__ float b2f(u16 x) {
  union { u32 u; float f; } c; c.u = ((u32)x) << 16; return c.f;
}
__device__ __forceinline__ u16 f2b(float f) {
  union { float f; u32 u; } c; c.f = f;
  u32 u = c.u;
  return (u16)((u + 0x7FFFu + ((u >> 16) & 1u)) >> 16);
}
__device__ __forceinline__ float sigf(float x) { return 1.f / (1.f + __expf(-x)); }
__device__ __forceinline__ float tanhfast(float x) {
  float e = __expf(2.f * x);
  return 1.f - 2.f / (e + 1.f);
}
__device__ __forceinline__ float clampf(float x, float b) {
  return fminf(fmaxf(x, -b), b);
}
__device__ __forceinline__ float loadin(const void* p, long i, u32 isf32) {
  return isf32 ? ((const float*)p)[i] : b2f(((const u16*)p)[i]);
}
// L2-bypassing coherent read (straight from coherence point)
__device__ __forceinline__ u32 l3_load(const u32* p) {
  u32 v;
  asm volatile("global_load_dword %0, %1, off sc0 sc1\n\ts_waitcnt vmcnt(0)"
               : "=v"(v) : "v"(p) : "memory");
  return v;
}
// Two coherent reads with a single latency exposure (pipelined, one drain).
__device__ __forceinline__ void l3_load2(const u32* p0, const u32* p1,
                                         u32& v0, u32& v1) {
  asm volatile("global_load_dword %0, %2, off sc0 sc1\n\t"
               "global_load_dword %1, %3, off sc0 sc1\n\t"
               "s_waitcnt vmcnt(0)"
               : "=&v"(v0), "=&v"(v1) : "v"(p0), "v"(p1) : "memory");
}
// Write-through store (never lingers dirty in local L2)
__device__ __forceinline__ void l3_store(u32* p, u32 v) {
  asm volatile("global_store_dword %0, %1, off sc0 sc1" :: "v"(p), "v"(v) : "memory");
}
__device__ __forceinline__ void vm_drain() {
  asm volatile("s_waitcnt vmcnt(0)" ::: "memory");
}
// LDS-writes-visible barrier that does NOT force a vmcnt(0) drain: in-flight
// global loads (whose waits the COMPILER inserts at their consuming stores)
// may stay outstanding across it. Classic write -> lgkmcnt(0) -> barrier -> read.
__device__ __forceinline__ void lds_fence_barrier() {
  asm volatile("s_waitcnt lgkmcnt(0)\n\ts_barrier" ::: "memory");
}

// Layouts:
//  hsT[t][w8][b][j]  u16 idx = t*32768 + w8*512 + b*8 + j   (w8=64 col-octets)
//  xT [s][k8][b][j]  u16 idx = s*20480 + k8*512 + b*8 + j   (k8=40 col-octets)
// Tiles are contiguous per step; staged 16B/thread/chunk; A-frag reads in LDS
// are 16B-contiguous per lane (T layout matches global).

// ---------------------------------------------------------------------------
__global__ __launch_bounds__(256) void detect_kernel(const u16* __restrict__ bih0,
                                                     u32* __restrict__ flag) {
  __shared__ u32 cnts[2];
  if (threadIdx.x < 2) cnts[threadIdx.x] = 0;
  __syncthreads();
  u32 huge = 0, zeros = 0;
  for (int i = threadIdx.x; i < 2048; i += 256) {
    u16 v = bih0[i];
    u32 e = (v >> 7) & 0xFFu;
    if (e >= 0xC0u) huge++;
    if (v == 0) zeros++;
  }
  atomicAdd(&cnts[0], huge);
  atomicAdd(&cnts[1], zeros);
  __syncthreads();
  if (threadIdx.x == 0) flag[0] = (cnts[0] >= 8u || cnts[1] >= 600u) ? 1u : 0u;
}

// ---------------------------------------------------------------------------
__global__ __launch_bounds__(256) void prep_kernel(
    const void* __restrict__ Wih0, const void* __restrict__ Whh0,
    const void* __restrict__ bih0, const void* __restrict__ bhh0,
    const void* __restrict__ Wih1, const void* __restrict__ Whh1,
    const void* __restrict__ bih1, const void* __restrict__ bhh1,
    const void* __restrict__ W1, const void* __restrict__ b1,
    const void* __restrict__ W2, const void* __restrict__ b2,
    const void* __restrict__ Wf, const void* __restrict__ bfv,
    u16* __restrict__ Wcat0, u16* __restrict__ Wcat1,
    float* __restrict__ biasR0, float* __restrict__ biasR1,
    u16* __restrict__ W1c, float* __restrict__ b1c,
    float* __restrict__ W2c, float* __restrict__ b2c,
    float* __restrict__ Wfc, float* __restrict__ bfc,
    const u32* __restrict__ flag)
{
  const u32 isf32 = flag[0];
  const int gid = blockIdx.x * 256 + threadIdx.x;
  const int gsz = gridDim.x * 256;
  for (int i = gid; i < 2048 * 832; i += gsz) {
    int np = i / 832, k = i - np * 832;
    int g = np & 3, j = np >> 2;
    long orig = g * 512 + j;
    u16 v;
    if (k < 320) v = (k < 300) ? f2b(loadin(Wih0, orig * 300 + k, isf32)) : (u16)0;
    else         v = f2b(loadin(Whh0, orig * 512 + (k - 320), isf32));
    Wcat0[i] = v;
  }
  for (int i = gid; i < 2048 * 1024; i += gsz) {
    int np = i >> 10, k = i & 1023;
    int g = np & 3, j = np >> 2;
    long orig = g * 512 + j;
    Wcat1[i] = (k < 512) ? f2b(loadin(Wih1, orig * 512 + k, isf32))
                         : f2b(loadin(Whh1, orig * 512 + (k - 512), isf32));
  }
  for (int i = gid; i < 2048; i += gsz) {
    int g = i & 3, j = i >> 2;
    long orig = g * 512 + j;
    biasR0[i] = loadin(bih0, orig, isf32) + loadin(bhh0, orig, isf32);
    biasR1[i] = loadin(bih1, orig, isf32) + loadin(bhh1, orig, isf32);
  }
  for (int i = gid; i < 256 * 1024; i += gsz) W1c[i] = f2b(loadin(W1, i, isf32));
  for (int i = gid; i < 256; i += gsz) {
    b1c[i] = loadin(b1, i, isf32);
    W2c[i] = loadin(W2, i, isf32);
  }
  for (int i = gid; i < 1024; i += gsz) Wfc[i] = loadin(Wf, i, isf32);
  if (gid == 0) {
    b2c[0] = loadin(b2, 0, isf32);
    bfc[0] = loadin(bfv, 0, isf32);
  }
}

// ---------------------------------------------------------------------------
// gather -> xT layout: xT[s][c>>3][b][c&7]
// ---------------------------------------------------------------------------
__global__ __launch_bounds__(256) void gather_kernel(
    const int* __restrict__ xi, const void* __restrict__ embed,
    u16* __restrict__ xT, const u32* __restrict__ flag)
{
  const u32 isf32 = flag[0];
  const int r = blockIdx.x * 4 + (threadIdx.x >> 6);
  const int lane = threadIdx.x & 63;
  const int b = r & 63, s = r >> 6;
  const int idx = xi[b * 1024 + s];
  u16* dst = xT + (u64)s * 20480 + b * 8;
  if (!isf32) {
    const u16* src = (const u16*)embed + (u64)idx * 300;
    for (int c = lane; c < 300; c += 64) dst[(c >> 3) * 512 + (c & 7)] = src[c];
  } else {
    const float* src = (const float*)embed + (u64)idx * 300;
    for (int c = lane; c < 300; c += 64) dst[(c >> 3) * 512 + (c & 7)] = f2b(src[c]);
  }
  for (int c = 300 + lane; c < 320; c += 64) dst[(c >> 3) * 512 + (c & 7)] = 0;
}

// ---------------------------------------------------------------------------
// Fused persistent 2-layer LSTM. 128 WGs: 0-63 layer0, 64-127 layer1 (lag 1).
// R0 skeleton (batch-split waves, full-K per wave, weights in LDS, 64 flag
// lines, proven sync) + fence-pinned prefetch:
//  - stage loads are PLAIN C++ loads into local arrays (compiler inserts the
//    dependency waits at the LDS stores -> spill-safe, unlike hand vmcnt)
//  - fences (__syncthreads / memory-clobber poll asm) pin issue points: loads
//    cannot sink past them, cannot be rematerialized across them (hs aliased)
//  - layer-0 x loads issue BEFORE the flag wait (overlap poll discovery)
//  - h(t-1) loads issue right after the wait; their LDS stores sit after the
//    x-MFMA phase -> h latency hides under x stage + compute
//  - one raw lgkmcnt-only barrier between x stores and x-MFMAs keeps the h
//    loads in flight (all other barriers are plain __syncthreads)
//  - layer-1 polls cross+own flags in ONE combined discovery (l3_load2)
// ---------------------------------------------------------------------------
__global__ __launch_bounds__(256, 1) void lstm_fused(
    const u16* __restrict__ xT,
    const u16* __restrict__ Wcat0, const float* __restrict__ biasR0,
    const u16* __restrict__ Wcat1, const float* __restrict__ biasR1,
    u16* __restrict__ h0sT, u16* __restrict__ h1sT,
    u32* __restrict__ flags0, u32* __restrict__ flags1, int S)
{
  __shared__ __align__(16) u16 ldsW[32 * 1032];   // weight slice, padded pitch
  __shared__ __align__(16) u16 ldsHT[32768];      // x/h tile, T layout (64 KB)
  __shared__ float ldsZ[64 * 33];

  const int layer = blockIdx.x >> 6;
  const int w = blockIdx.x & 63;
  const int KX = layer ? 512 : 320;
  const u16* Wcat = layer ? Wcat1 : Wcat0;
  const float* biasR = layer ? biasR1 : biasR0;
  u16* hs = layer ? h1sT : h0sT;
  u32* fown = layer ? flags1 : flags0;

  const int tid = threadIdx.x;
  const int lane = tid & 63;
  const int wv = tid >> 6;
  const int Kt = KX + 512;
  const int PW = Kt + 8;
  const int nu32 = Kt >> 1;

  {   // weight slice rows w*32..w*32+31 -> LDS (one-time)
    const u32* src = (const u32*)Wcat;
    u32* dst = (u32*)ldsW;
    const int pw2 = PW >> 1;
    for (int i = tid; i < 32 * nu32; i += 256) {
      int r = i / nu32, c = i - r * nu32;
      dst[r * pw2 + c] = src[(u64)(w * 32 + r) * nu32 + c];
    }
  }
  __syncthreads();

  const int nksX = KX >> 5;                 // 10 or 16
  const int lrow = lane & 15;
  const int kq = lane >> 4;
  const int arow = (wv * 16 + lrow) * 8;    // A-frag base (b*8) in ldsHT
  f32x4* ldsV = (f32x4*)ldsHT;
  const int gb = tid >> 2;                  // gates: batch row
  const int gj0 = (tid & 3) * 2;            // gates: first h-col pair
  float c0 = 0.f, c1 = 0.f;                 // c-state, register-resident

  for (int t = 0; t < S; ++t) {
    f32x4 acc0 = {0.f, 0.f, 0.f, 0.f};
    f32x4 acc1 = {0.f, 0.f, 0.f, 0.f};
    f32x4 tx[16], th[16];

    if (layer == 0) {
      // x loads issue pre-wait (xT static); latency overlaps poll discovery
      {
        const f32x4* gx = (const f32x4*)(xT + (u64)t * 20480);
#pragma unroll
        for (int i = 0; i < 10; ++i) tx[i] = gx[i * 256 + tid];
      }
      if (t > 0) {
        if (wv == 0) {
          const u32* fp = flags0 + lane * 16;
          const u32 tgt = (u32)t;
          while (!__all((int)(l3_load(fp) >= tgt))) __builtin_amdgcn_s_sleep(1);
        }
        __syncthreads();
        // h(t-1) loads issue now; compiler waits for them at their LDS
        // stores (after the x-MFMA phase) -> latency hidden
        const f32x4* gh = (const f32x4*)(hs + (u64)(t - 1) * 32768);
#pragma unroll
        for (int i = 0; i < 16; ++i) th[i] = gh[i * 256 + tid];
      }
#pragma unroll
      for (int i = 0; i < 10; ++i) ldsV[i * 256 + tid] = tx[i];
    } else {
      // combined cross+own wait: one discovery period covers both
      if (wv == 0) {
        const u32* fpc = flags0 + lane * 16;
        const u32* fpo = flags1 + lane * 16;
        const u32 tgtc = (u32)(t + 1), tgto = (u32)t;
        for (;;) {
          u32 vc, vo;
          if (t > 0) l3_load2(fpc, fpo, vc, vo);
          else { vc = l3_load(fpc); vo = tgto; }
          if (__all((int)((vc >= tgtc) && (vo >= tgto)))) break;
          __builtin_amdgcn_s_sleep(1);
        }
      }
      __syncthreads();
      {
        const f32x4* gx = (const f32x4*)(h0sT + (u64)t * 32768);
#pragma unroll
        for (int i = 0; i < 16; ++i) tx[i] = gx[i * 256 + tid];
      }
      if (t > 0) {
        const f32x4* gh = (const f32x4*)(h1sT + (u64)(t - 1) * 32768);
#pragma unroll
        for (int i = 0; i < 16; ++i) th[i] = gh[i * 256 + tid];
      }
#pragma unroll
      for (int i = 0; i < 16; ++i) ldsV[i * 256 + tid] = tx[i];
    }
    lds_fence_barrier();   // x tile visible; th loads stay in flight

    // ---- x / h0 projection MFMAs (h loads flying underneath)
    for (int ks = 0; ks < nksX; ++ks) {
      int k = ks * 32 + kq * 8;
      bf16x8 a  = *(const bf16x8*)&ldsHT[(ks * 4 + kq) * 512 + arow];
      bf16x8 b0 = *(const bf16x8*)&ldsW[lrow * PW + k];
      bf16x8 b1 = *(const bf16x8*)&ldsW[(16 + lrow) * PW + k];
      acc0 = __builtin_amdgcn_mfma_f32_16x16x32_bf16(a, b0, acc0, 0, 0, 0);
      acc1 = __builtin_amdgcn_mfma_f32_16x16x32_bf16(a, b1, acc1, 0, 0, 0);
    }

    // ---- recurrent phase
    if (t > 0) {
      __syncthreads();     // all waves done reading x tile
#pragma unroll
      for (int i = 0; i < 16; ++i) ldsV[i * 256 + tid] = th[i];  // waits th here
      __syncthreads();
      for (int ks = 0; ks < 16; ++ks) {
        int k = KX + ks * 32 + kq * 8;
        bf16x8 a  = *(const bf16x8*)&ldsHT[(ks * 4 + kq) * 512 + arow];
        bf16x8 b0 = *(const bf16x8*)&ldsW[lrow * PW + k];
        bf16x8 b1 = *(const bf16x8*)&ldsW[(16 + lrow) * PW + k];
        acc0 = __builtin_amdgcn_mfma_f32_16x16x32_bf16(a, b0, acc0, 0, 0, 0);
        acc1 = __builtin_amdgcn_mfma_f32_16x16x32_bf16(a, b1, acc1, 0, 0, 0);
      }
    }

    // ---- z tile -> LDS (C layout: col=lane&15, row=quad*4+reg)
    {
      int col = lane & 15, q = lane >> 4;
#pragma unroll
      for (int r = 0; r < 4; ++r) {
        int m = wv * 16 + q * 4 + r;
        ldsZ[m * 33 + col] = acc0[r];
        ldsZ[m * 33 + 16 + col] = acc1[r];
      }
    }
    __syncthreads();

    // ---- gates + contiguous full-line h store (c-state in registers)
    {
      float hv[2];
#pragma unroll
      for (int q2 = 0; q2 < 2; ++q2) {
        int cb = (gj0 + q2) * 4;
        float zi = clampf(ldsZ[gb * 33 + cb + 0] + biasR[w * 32 + cb + 0], 30.f);
        float zf = clampf(ldsZ[gb * 33 + cb + 1] + biasR[w * 32 + cb + 1], 30.f);
        float zg = clampf(ldsZ[gb * 33 + cb + 2] + biasR[w * 32 + cb + 2], 30.f);
        float zo = clampf(ldsZ[gb * 33 + cb + 3] + biasR[w * 32 + cb + 3], 30.f);
        float co = q2 ? c1 : c0;
        float cn = clampf(sigf(zf) * co + sigf(zi) * tanhfast(zg), 64.f);
        if (q2) c1 = cn; else c0 = cn;
        hv[q2] = clampf(sigf(zo) * tanhfast(cn), 1.f);
      }
      u32 packed = (u32)f2b(hv[0]) | ((u32)f2b(hv[1]) << 16);
      l3_store((u32*)hs + (u64)t * 16384 + w * 256 + tid, packed);
      vm_drain();
    }
    __syncthreads();            // all threads' h stores at coherence point
    if (tid == 0) l3_store(fown + w * 16, (u32)(t + 1));
  }
}

// ---------------------------------------------------------------------------
// gemm over hsT A: C[M=65536,N=256](bf16) = A_hsT @ B[N,K=512]^T. 128x128.
// ---------------------------------------------------------------------------
__global__ __launch_bounds__(256, 1) void gemm_hA(
    const u16* __restrict__ A,
    const u16* __restrict__ B, int ldb,
    u16* __restrict__ C, int ldc, int K)
{
  __shared__ __align__(16) u16 As[128 * 40];
  __shared__ __align__(16) u16 Bs[128 * 40];
  const int tid = threadIdx.x;
  const int bn = blockIdx.x * 128;
  const int bm = blockIdx.y * 128;
  const int lane = tid & 63;
  const int wv = tid >> 6;
  const int mh = wv >> 1, nh = wv & 1;
  const int lrow = lane & 15, kq = lane >> 4;
  const int sr = tid >> 1, sh = (tid & 1) * 16;
  const int m_ = bm + sr, s_ = m_ >> 6, bb = m_ & 63;
  f32x4 acc[4][4];
#pragma unroll
  for (int i = 0; i < 4; ++i)
#pragma unroll
    for (int j = 0; j < 4; ++j) acc[i][j] = {0.f, 0.f, 0.f, 0.f};

  for (int k0 = 0; k0 < K; k0 += 32) {
    const u16* ap = A + (u64)s_ * 32768 + (u64)((k0 + sh) >> 3) * 512 + bb * 8;
    *(bf16x8*)&As[sr * 40 + sh]     = *(const bf16x8*)ap;
    *(bf16x8*)&As[sr * 40 + sh + 8] = *(const bf16x8*)(ap + 512);
    *(bf16x8*)&Bs[sr * 40 + sh]     = *(const bf16x8*)(B + (u64)(bn + sr) * ldb + k0 + sh);
    *(bf16x8*)&Bs[sr * 40 + sh + 8] = *(const bf16x8*)(B + (u64)(bn + sr) * ldb + k0 + sh + 8);
    __syncthreads();
    bf16x8 af[4], bfr[4];
#pragma unroll
    for (int mt = 0; mt < 4; ++mt)
      af[mt] = *(const bf16x8*)&As[(mh * 64 + mt * 16 + lrow) * 40 + kq * 8];
#pragma unroll
    for (int nt = 0; nt < 4; ++nt)
      bfr[nt] = *(const bf16x8*)&Bs[(nh * 64 + nt * 16 + lrow) * 40 + kq * 8];
#pragma unroll
    for (int mt = 0; mt < 4; ++mt)
#pragma unroll
      for (int nt = 0; nt < 4; ++nt)
        acc[mt][nt] = __builtin_amdgcn_mfma_f32_16x16x32_bf16(af[mt], bfr[nt], acc[mt][nt], 0, 0, 0);
    __syncthreads();
  }
#pragma unroll
  for (int mt = 0; mt < 4; ++mt)
#pragma unroll
    for (int nt = 0; nt < 4; ++nt)
#pragma unroll
      for (int r = 0; r < 4; ++r) {
        int m = bm + mh * 64 + mt * 16 + kq * 4 + r;
        int n = bn + nh * 64 + nt * 16 + lrow;
        C[(u64)m * ldc + n] = f2b(clampf(acc[mt][nt][r], 60.f));
      }
}

// ---------------------------------------------------------------------------
__global__ __launch_bounds__(256) void part1_kernel(
    const u16* __restrict__ h1sT, const u16* __restrict__ W1c,
    const float* __restrict__ b1c, float* __restrict__ part1)
{
  __shared__ float hN[512];
  const int b = blockIdx.x;
  const int l = threadIdx.x;
  for (int i = l; i < 512; i += 256)
    hN[i] = b2f(h1sT[(u64)1023 * 32768 + (i >> 3) * 512 + b * 8 + (i & 7)]);
  __syncthreads();
  const u16* wrow = W1c + (u64)l * 1024;
  float acc = b1c[l];
  for (int k = 0; k < 512; ++k) acc += hN[k] * b2f(wrow[k]);
  part1[b * 256 + l] = clampf(acc, 60.f);
}

// ---------------------------------------------------------------------------
__global__ __launch_bounds__(256) void escore_kernel(
    const float* __restrict__ part1, const u16* __restrict__ part2,
    const float* __restrict__ W2c, const float* __restrict__ b2c,
    float* __restrict__ e)
{
  const int m = blockIdx.x * 4 + (threadIdx.x >> 6);
  const int lane = threadIdx.x & 63;
  const int b = m & 63, s = m >> 6;
  float acc = 0.f;
  for (int l = lane; l < 256; l += 64)
    acc += tanhfast(part1[b * 256 + l] + b2f(part2[(u64)m * 256 + l])) * W2c[l];
#pragma unroll
  for (int off = 32; off; off >>= 1) acc += __shfl_down(acc, off, 64);
  if (lane == 0) e[b * 1024 + s] = clampf(acc + b2c[0], 60.f);
}

// ---------------------------------------------------------------------------
__global__ __launch_bounds__(256) void finish_kernel(
    const float* __restrict__ e, const u16* __restrict__ h1sT,
    const float* __restrict__ Wfc, const float* __restrict__ bfc,
    void* __restrict__ dout, const u32* __restrict__ flag)
{
  __shared__ float sw[1024];
  __shared__ float red[4];
  __shared__ float hN[512];
  const u32 isf32 = flag[0];
  const int b = blockIdx.x;
  const int tid = threadIdx.x;
  const int lane = tid & 63, wv = tid >> 6;

  float mx = -1e30f;
  for (int s = tid; s < 1024; s += 256) {
    float v = e[b * 1024 + s];
    sw[s] = v;
    mx = fmaxf(mx, v);
  }
#pragma unroll
  for (int off = 1; off < 64; off <<= 1) mx = fmaxf(mx, __shfl_xor(mx, off, 64));
  if (lane == 0) red[wv] = mx;
  __syncthreads();
  mx = fmaxf(fmaxf(red[0], red[1]), fmaxf(red[2], red[3]));
  __syncthreads();

  float sum = 0.f;
  for (int s = tid; s < 1024; s += 256) {
    float p = __expf(sw[s] - mx);
    sw[s] = p;
    sum += p;
  }
#pragma unroll
  for (int off = 1; off < 64; off <<= 1) sum += __shfl_xor(sum, off, 64);
  if (lane == 0) red[wv] = sum;
  __syncthreads();
  sum = red[0] + red[1] + red[2] + red[3];
  float inv = 1.f / sum;
  for (int s = tid; s < 1024; s += 256) {
    float wn = sw[s] * inv;
    sw[s] = wn;
    if (isf32) ((float*)dout)[b * 1024 + s] = wn;
    else       ((u16*)dout)[b * 1024 + s] = f2b(wn);
  }
  for (int i = tid; i < 512; i += 256)
    hN[i] = b2f(h1sT[(u64)1023 * 32768 + (i >> 3) * 512 + b * 8 + (i & 7)]);
  __syncthreads();

  const int c0 = tid, c1 = tid + 256;
  const u64 off0 = (u64)(c0 >> 3) * 512 + b * 8 + (c0 & 7);
  const u64 off1 = (u64)(c1 >> 3) * 512 + b * 8 + (c1 & 7);
  float a0 = 0.f, a1 = 0.f;
  for (int s = 0; s < 1024; ++s) {
    const u16* hr = h1sT + (u64)s * 32768;
    float wn = sw[s];
    a0 += wn * b2f(hr[off0]);
    a1 += wn * b2f(hr[off1]);
  }
  float part = a0 * Wfc[c0] + a1 * Wfc[c1] + hN[c0] * Wfc[512 + c0] + hN[c1] * Wfc[512 + c1];
#pragma unroll
  for (int off = 1; off < 64; off <<= 1) part += __shfl_xor(part, off, 64);
  __syncthreads();
  if (lane == 0) red[wv] = part;
  __syncthreads();
  if (tid == 0) {
    float tot = clampf(red[0] + red[1] + red[2] + red[3] + bfc[0], 30.f);
    float o = sigf(tot);
    if (isf32) ((float*)dout)[65536 + b] = o;
    else       ((u16*)dout)[65536 + b] = f2b(o);
  }
}

// ---------------------------------------------------------------------------
extern "C" void kernel_launch(void* const* d_in, const int* in_sizes, int n_in,
                              void* d_out, int out_size, void* d_ws, size_t ws_size,
                              hipStream_t stream) {
  const int* x_index = (const int*)d_in[0];
  const void* embed = d_in[1];
  const void* Wih0 = d_in[2];
  const void* Whh0 = d_in[3];
  const void* bih0 = d_in[4];
  const void* bhh0 = d_in[5];
  const void* Wih1 = d_in[6];
  const void* Whh1 = d_in[7];
  const void* bih1 = d_in[8];
  const void* bhh1 = d_in[9];
  const void* W1 = d_in[10];
  const void* b1 = d_in[11];
  const void* W2 = d_in[12];
  const void* b2 = d_in[13];
  const void* Wf = d_in[14];
  const void* bfv = d_in[15];

  char* ws = (char*)d_ws;
  size_t off = 0;
  auto alloc = [&](size_t bytes) -> char* {
    char* p = ws + off;
    off += (bytes + 255) & ~(size_t)255;
    return p;
  };
  u32* flags0    = (u32*)alloc(64 * 16 * 4);   // one flag per 64B line
  u32* flags1    = (u32*)alloc(64 * 16 * 4);
  u32* flag      = (u32*)alloc(256);
  float* biasR0  = (float*)alloc(2048 * 4);
  float* biasR1  = (float*)alloc(2048 * 4);
  float* part1   = (float*)alloc(64 * 256 * 4);
  float* e       = (float*)alloc(64 * 1024 * 4);
  float* b1c     = (float*)alloc(256 * 4);
  float* W2c     = (float*)alloc(256 * 4);
  float* b2c     = (float*)alloc(16);
  float* Wfc     = (float*)alloc(1024 * 4);
  float* bfc     = (float*)alloc(16);
  u16* W1c       = (u16*)alloc((size_t)256 * 1024 * 2);
  u16* Wcat0     = (u16*)alloc((size_t)2048 * 832 * 2);
  u16* Wcat1     = (u16*)alloc((size_t)2048 * 1024 * 2);
  u16* xT        = (u16*)alloc((size_t)65536 * 320 * 2);
  u16* h0sT      = (u16*)alloc((size_t)65536 * 512 * 2);
  u16* h1sT      = (u16*)alloc((size_t)65536 * 512 * 2);
  u16* part2     = (u16*)alloc((size_t)65536 * 256 * 2);
  (void)ws_size; (void)in_sizes; (void)n_in; (void)out_size;

  hipMemsetAsync(flags0, 0, 64 * 16 * 4 * 2, stream);  // flags0 + flags1
  hipLaunchKernelGGL(detect_kernel, dim3(1), dim3(256), 0, stream,
                     (const u16*)bih0, flag);
  hipLaunchKernelGGL(prep_kernel, dim3(512), dim3(256), 0, stream,
                     Wih0, Whh0, bih0, bhh0, Wih1, Whh1, bih1, bhh1,
                     W1, b1, W2, b2, Wf, bfv,
                     Wcat0, Wcat1, biasR0, biasR1,
                     W1c, b1c, W2c, b2c, Wfc, bfc, flag);
  hipLaunchKernelGGL(gather_kernel, dim3(16384), dim3(256), 0, stream,
                     x_index, embed, xT, flag);
  hipLaunchKernelGGL(lstm_fused, dim3(128), dim3(256), 0, stream,
                     xT, Wcat0, biasR0, Wcat1, biasR1,
                     h0sT, h1sT, flags0, flags1, 1024);
  hipLaunchKernelGGL(part1_kernel, dim3(64), dim3(256), 0, stream,
                     h1sT, W1c, b1c, part1);
  hipLaunchKernelGGL(gemm_hA, dim3(2, 512), dim3(256), 0, stream,
                     h1sT, W1c + 512, 1024, part2, 256, 512);
  hipLaunchKernelGGL(escore_kernel, dim3(16384), dim3(256), 0, stream,
                     part1, part2, W2c, b2c, e);
  hipLaunchKernelGGL(finish_kernel, dim3(64), dim3(256), 0, stream,
                     e, h1sT, Wfc, bfc, d_out, flag);
}

// Round 7
// 5562.075 us; speedup vs baseline: 1.4933x; 1.1491x over previous
//
#include <hip/hip_runtime.h>

typedef unsigned short u16;
typedef unsigned int u32;
typedef unsigned long long u64;
typedef __attribute__((ext_vector_type(8))) short bf16x8;
typedef __attribute__((ext_vector_type(4))) float f32x4;

__device__ __forceinline__ float b2f(u16 x) {
  union { u32 u; float f; } c; c.u = ((u32)x) << 16; return c.f;
}
__device__ __forceinline__ u16 f2b(float f) {
  union { float f; u32 u; } c; c.f = f;
  u32 u = c.u;
  return (u16)((u + 0x7FFFu + ((u >> 16) & 1u)) >> 16);
}
__device__ __forceinline__ float sigf(float x) { return 1.f / (1.f + __expf(-x)); }
__device__ __forceinline__ float tanhfast(float x) {
  float e = __expf(2.f * x);
  return 1.f - 2.f / (e + 1.f);
}
__device__ __forceinline__ float clampf(float x, float b) {
  return fminf(fmaxf(x, -b), b);
}
__device__ __forceinline__ float loadin(const void* p, long i, u32 isf32) {
  return isf32 ? ((const float*)p)[i] : b2f(((const u16*)p)[i]);
}
// L2-bypassing coherent read (straight from coherence point)
__device__ __forceinline__ u32 l3_load(const u32* p) {
  u32 v;
  asm volatile("global_load_dword %0, %1, off sc0 sc1\n\ts_waitcnt vmcnt(0)"
               : "=v"(v) : "v"(p) : "memory");
  return v;
}
// Write-through store (never lingers dirty in local L2)
__device__ __forceinline__ void l3_store(u32* p, u32 v) {
  asm volatile("global_store_dword %0, %1, off sc0 sc1" :: "v"(p), "v"(v) : "memory");
}
__device__ __forceinline__ void vm_drain() {
  asm volatile("s_waitcnt vmcnt(0)" ::: "memory");
}

// Latency-parallel staging: N 16B chunks per thread, ALL loads issued before
// any LDS store -> single latency exposure instead of N/unroll batches.
template <int N>
__device__ __forceinline__ void stageN(const f32x4* __restrict__ g,
                                       f32x4* __restrict__ l, int tid) {
  f32x4 t[N];
#pragma unroll
  for (int i = 0; i < N; ++i) t[i] = g[i * 256 + tid];
#pragma unroll
  for (int i = 0; i < N; ++i) l[i * 256 + tid] = t[i];
}

// Layouts:
//  hsT[t][w8][b][j]  u16 idx = t*32768 + w8*512 + b*8 + j   (w8=64 col-octets)
//  xT [s][k8][b][j]  u16 idx = s*20480 + k8*512 + b*8 + j   (k8=40 col-octets)
// Tiles contiguous per step -> register-batched staging; A-frag reads in LDS
// are 16B-contiguous per lane.

// ---------------------------------------------------------------------------
__global__ __launch_bounds__(256) void detect_kernel(const u16* __restrict__ bih0,
                                                     u32* __restrict__ flag) {
  __shared__ u32 cnts[2];
  if (threadIdx.x < 2) cnts[threadIdx.x] = 0;
  __syncthreads();
  u32 huge = 0, zeros = 0;
  for (int i = threadIdx.x; i < 2048; i += 256) {
    u16 v = bih0[i];
    u32 e = (v >> 7) & 0xFFu;
    if (e >= 0xC0u) huge++;
    if (v == 0) zeros++;
  }
  atomicAdd(&cnts[0], huge);
  atomicAdd(&cnts[1], zeros);
  __syncthreads();
  if (threadIdx.x == 0) flag[0] = (cnts[0] >= 8u || cnts[1] >= 600u) ? 1u : 0u;
}

// ---------------------------------------------------------------------------
__global__ __launch_bounds__(256) void prep_kernel(
    const void* __restrict__ Wih0, const void* __restrict__ Whh0,
    const void* __restrict__ bih0, const void* __restrict__ bhh0,
    const void* __restrict__ Wih1, const void* __restrict__ Whh1,
    const void* __restrict__ bih1, const void* __restrict__ bhh1,
    const void* __restrict__ W1, const void* __restrict__ b1,
    const void* __restrict__ W2, const void* __restrict__ b2,
    const void* __restrict__ Wf, const void* __restrict__ bfv,
    u16* __restrict__ Wcat0, u16* __restrict__ Wcat1,
    float* __restrict__ biasR0, float* __restrict__ biasR1,
    u16* __restrict__ W1c, float* __restrict__ b1c,
    float* __restrict__ W2c, float* __restrict__ b2c,
    float* __restrict__ Wfc, float* __restrict__ bfc,
    const u32* __restrict__ flag)
{
  const u32 isf32 = flag[0];
  const int gid = blockIdx.x * 256 + threadIdx.x;
  const int gsz = gridDim.x * 256;
  for (int i = gid; i < 2048 * 832; i += gsz) {
    int np = i / 832, k = i - np * 832;
    int g = np & 3, j = np >> 2;
    long orig = g * 512 + j;
    u16 v;
    if (k < 320) v = (k < 300) ? f2b(loadin(Wih0, orig * 300 + k, isf32)) : (u16)0;
    else         v = f2b(loadin(Whh0, orig * 512 + (k - 320), isf32));
    Wcat0[i] = v;
  }
  for (int i = gid; i < 2048 * 1024; i += gsz) {
    int np = i >> 10, k = i & 1023;
    int g = np & 3, j = np >> 2;
    long orig = g * 512 + j;
    Wcat1[i] = (k < 512) ? f2b(loadin(Wih1, orig * 512 + k, isf32))
                         : f2b(loadin(Whh1, orig * 512 + (k - 512), isf32));
  }
  for (int i = gid; i < 2048; i += gsz) {
    int g = i & 3, j = i >> 2;
    long orig = g * 512 + j;
    biasR0[i] = loadin(bih0, orig, isf32) + loadin(bhh0, orig, isf32);
    biasR1[i] = loadin(bih1, orig, isf32) + loadin(bhh1, orig, isf32);
  }
  for (int i = gid; i < 256 * 1024; i += gsz) W1c[i] = f2b(loadin(W1, i, isf32));
  for (int i = gid; i < 256; i += gsz) {
    b1c[i] = loadin(b1, i, isf32);
    W2c[i] = loadin(W2, i, isf32);
  }
  for (int i = gid; i < 1024; i += gsz) Wfc[i] = loadin(Wf, i, isf32);
  if (gid == 0) {
    b2c[0] = loadin(b2, 0, isf32);
    bfc[0] = loadin(bfv, 0, isf32);
  }
}

// ---------------------------------------------------------------------------
// gather -> xT layout: xT[s][c>>3][b][c&7]
// ---------------------------------------------------------------------------
__global__ __launch_bounds__(256) void gather_kernel(
    const int* __restrict__ xi, const void* __restrict__ embed,
    u16* __restrict__ xT, const u32* __restrict__ flag)
{
  const u32 isf32 = flag[0];
  const int r = blockIdx.x * 4 + (threadIdx.x >> 6);
  const int lane = threadIdx.x & 63;
  const int b = r & 63, s = r >> 6;
  const int idx = xi[b * 1024 + s];
  u16* dst = xT + (u64)s * 20480 + b * 8;
  if (!isf32) {
    const u16* src = (const u16*)embed + (u64)idx * 300;
    for (int c = lane; c < 300; c += 64) dst[(c >> 3) * 512 + (c & 7)] = src[c];
  } else {
    const float* src = (const float*)embed + (u64)idx * 300;
    for (int c = lane; c < 300; c += 64) dst[(c >> 3) * 512 + (c & 7)] = f2b(src[c]);
  }
  for (int c = 300 + lane; c < 320; c += 64) dst[(c >> 3) * 512 + (c & 7)] = 0;
}

// ---------------------------------------------------------------------------
// Fused persistent 2-layer LSTM. 128 WGs: 0-63 layer0, 64-127 layer1.
// EXACT R0 skeleton (batch-split waves, full-K per wave, weights in LDS,
// stageN batching, 64 flag lines, plain __syncthreads) with ONE change:
// the own-layer flag wait is moved AFTER the independent projection phase.
//  - L0: stage-x + MFMA-x first (xT static), then poll own flags. The
//    store->flag->poll round trip of step t-1 hides behind the x phase.
//  - L1: cross poll at top (L0 free-runs ahead -> first-hit), stage+MFMA
//    h0[t], THEN poll own flags (posted ~1.5k cy earlier by peers ->
//    first-hit), stage+MFMA h1[t-1].
// c-state in registers (validated R1-R6). Everything else byte-identical.
// ---------------------------------------------------------------------------
__global__ __launch_bounds__(256, 1) void lstm_fused(
    const u16* __restrict__ xT,
    const u16* __restrict__ Wcat0, const float* __restrict__ biasR0,
    const u16* __restrict__ Wcat1, const float* __restrict__ biasR1,
    u16* __restrict__ h0sT, u16* __restrict__ h1sT,
    u32* __restrict__ flags0, u32* __restrict__ flags1, int S)
{
  __shared__ __align__(16) u16 ldsW[32 * 1032];   // weight slice, padded pitch
  __shared__ __align__(16) u16 ldsHT[32768];      // x/h tile, T layout (64 KB)
  __shared__ float ldsZ[64 * 33];

  const int layer = blockIdx.x >> 6;
  const int w = blockIdx.x & 63;
  const int KX = layer ? 512 : 320;
  const u16* Wcat = layer ? Wcat1 : Wcat0;
  const float* biasR = layer ? biasR1 : biasR0;
  u16* hs = layer ? h1sT : h0sT;
  u32* fown = layer ? flags1 : flags0;

  const int tid = threadIdx.x;
  const int lane = tid & 63;
  const int wv = tid >> 6;
  const int Kt = KX + 512;
  const int PW = Kt + 8;
  const int nu32 = Kt >> 1;

  {   // weight slice rows w*32..w*32+31 -> LDS (one-time)
    const u32* src = (const u32*)Wcat;
    u32* dst = (u32*)ldsW;
    const int pw2 = PW >> 1;
    for (int i = tid; i < 32 * nu32; i += 256) {
      int r = i / nu32, c = i - r * nu32;
      dst[r * pw2 + c] = src[(u64)(w * 32 + r) * nu32 + c];
    }
  }
  __syncthreads();

  const int nksX = KX >> 5;                 // 10 or 16
  const int lrow = lane & 15;
  const int kq = lane >> 4;
  const int arow = (wv * 16 + lrow) * 8;    // A-frag base (b*8) in ldsHT
  f32x4* ldsV = (f32x4*)ldsHT;
  const int gb = tid >> 2;                  // gates: batch row
  const int gj0 = (tid & 3) * 2;            // gates: first h-col pair
  float c0 = 0.f, c1 = 0.f;                 // c-state, register-resident

  for (int t = 0; t < S; ++t) {
    f32x4 acc0 = {0.f, 0.f, 0.f, 0.f};
    f32x4 acc1 = {0.f, 0.f, 0.f, 0.f};

    // ---- phase 0: projection (no own-layer dependency)
    if (layer == 0) {
      stageN<10>((const f32x4*)(xT + (u64)t * 20480), ldsV, tid);
    } else {
      // cross wait: L0 free-runs ahead -> usually satisfied on first poll
      if (wv == 0) {
        const u32* fp = flags0 + lane * 16;
        const u32 tgt = (u32)(t + 1);
        while (!__all((int)(l3_load(fp) >= tgt))) __builtin_amdgcn_s_sleep(1);
      }
      __syncthreads();
      stageN<16>((const f32x4*)(h0sT + (u64)t * 32768), ldsV, tid);
    }
    __syncthreads();
    for (int ks = 0; ks < nksX; ++ks) {
      int k = ks * 32 + kq * 8;
      bf16x8 a  = *(const bf16x8*)&ldsHT[(ks * 4 + kq) * 512 + arow];
      bf16x8 b0 = *(const bf16x8*)&ldsW[lrow * PW + k];
      bf16x8 b1 = *(const bf16x8*)&ldsW[(16 + lrow) * PW + k];
      acc0 = __builtin_amdgcn_mfma_f32_16x16x32_bf16(a, b0, acc0, 0, 0, 0);
      acc1 = __builtin_amdgcn_mfma_f32_16x16x32_bf16(a, b1, acc1, 0, 0, 0);
    }

    // ---- own-layer wait AFTER projection: the store->flag->poll round trip
    // of the previous step has been propagating during the phase above.
    if (t > 0) {
      if (wv == 0) {
        const u32* fp = fown + lane * 16;
        const u32 tgt = (u32)t;
        while (!__all((int)(l3_load(fp) >= tgt))) __builtin_amdgcn_s_sleep(1);
      }
      __syncthreads();   // also: all waves done reading projection tile
      stageN<16>((const f32x4*)(hs + (u64)(t - 1) * 32768), ldsV, tid);
      __syncthreads();
      for (int ks = 0; ks < 16; ++ks) {
        int k = KX + ks * 32 + kq * 8;
        bf16x8 a  = *(const bf16x8*)&ldsHT[(ks * 4 + kq) * 512 + arow];
        bf16x8 b0 = *(const bf16x8*)&ldsW[lrow * PW + k];
        bf16x8 b1 = *(const bf16x8*)&ldsW[(16 + lrow) * PW + k];
        acc0 = __builtin_amdgcn_mfma_f32_16x16x32_bf16(a, b0, acc0, 0, 0, 0);
        acc1 = __builtin_amdgcn_mfma_f32_16x16x32_bf16(a, b1, acc1, 0, 0, 0);
      }
    }

    // ---- z tile -> LDS (C layout: col=lane&15, row=quad*4+reg)
    {
      int col = lane & 15, q = lane >> 4;
#pragma unroll
      for (int r = 0; r < 4; ++r) {
        int m = wv * 16 + q * 4 + r;
        ldsZ[m * 33 + col] = acc0[r];
        ldsZ[m * 33 + 16 + col] = acc1[r];
      }
    }
    __syncthreads();

    // ---- gates + contiguous full-line h store (c-state in registers)
    {
      float hv[2];
#pragma unroll
      for (int q2 = 0; q2 < 2; ++q2) {
        int cb = (gj0 + q2) * 4;
        float zi = clampf(ldsZ[gb * 33 + cb + 0] + biasR[w * 32 + cb + 0], 30.f);
        float zf = clampf(ldsZ[gb * 33 + cb + 1] + biasR[w * 32 + cb + 1], 30.f);
        float zg = clampf(ldsZ[gb * 33 + cb + 2] + biasR[w * 32 + cb + 2], 30.f);
        float zo = clampf(ldsZ[gb * 33 + cb + 3] + biasR[w * 32 + cb + 3], 30.f);
        float co = q2 ? c1 : c0;
        float cn = clampf(sigf(zf) * co + sigf(zi) * tanhfast(zg), 64.f);
        if (q2) c1 = cn; else c0 = cn;
        hv[q2] = clampf(sigf(zo) * tanhfast(cn), 1.f);
      }
      u32 packed = (u32)f2b(hv[0]) | ((u32)f2b(hv[1]) << 16);
      l3_store((u32*)hs + (u64)t * 16384 + w * 256 + tid, packed);
      vm_drain();
    }
    __syncthreads();            // all threads' h stores at coherence point
    if (tid == 0) l3_store(fown + w * 16, (u32)(t + 1));
  }
}

// ---------------------------------------------------------------------------
// gemm over hsT A: C[M=65536,N=256](bf16) = A_hsT @ B[N,K=512]^T. 128x128.
// ---------------------------------------------------------------------------
__global__ __launch_bounds__(256, 1) void gemm_hA(
    const u16* __restrict__ A,
    const u16* __restrict__ B, int ldb,
    u16* __restrict__ C, int ldc, int K)
{
  __shared__ __align__(16) u16 As[128 * 40];
  __shared__ __align__(16) u16 Bs[128 * 40];
  const int tid = threadIdx.x;
  const int bn = blockIdx.x * 128;
  const int bm = blockIdx.y * 128;
  const int lane = tid & 63;
  const int wv = tid >> 6;
  const int mh = wv >> 1, nh = wv & 1;
  const int lrow = lane & 15, kq = lane >> 4;
  const int sr = tid >> 1, sh = (tid & 1) * 16;
  const int m_ = bm + sr, s_ = m_ >> 6, bb = m_ & 63;
  f32x4 acc[4][4];
#pragma unroll
  for (int i = 0; i < 4; ++i)
#pragma unroll
    for (int j = 0; j < 4; ++j) acc[i][j] = {0.f, 0.f, 0.f, 0.f};

  for (int k0 = 0; k0 < K; k0 += 32) {
    const u16* ap = A + (u64)s_ * 32768 + (u64)((k0 + sh) >> 3) * 512 + bb * 8;
    *(bf16x8*)&As[sr * 40 + sh]     = *(const bf16x8*)ap;
    *(bf16x8*)&As[sr * 40 + sh + 8] = *(const bf16x8*)(ap + 512);
    *(bf16x8*)&Bs[sr * 40 + sh]     = *(const bf16x8*)(B + (u64)(bn + sr) * ldb + k0 + sh);
    *(bf16x8*)&Bs[sr * 40 + sh + 8] = *(const bf16x8*)(B + (u64)(bn + sr) * ldb + k0 + sh + 8);
    __syncthreads();
    bf16x8 af[4], bfr[4];
#pragma unroll
    for (int mt = 0; mt < 4; ++mt)
      af[mt] = *(const bf16x8*)&As[(mh * 64 + mt * 16 + lrow) * 40 + kq * 8];
#pragma unroll
    for (int nt = 0; nt < 4; ++nt)
      bfr[nt] = *(const bf16x8*)&Bs[(nh * 64 + nt * 16 + lrow) * 40 + kq * 8];
#pragma unroll
    for (int mt = 0; mt < 4; ++mt)
#pragma unroll
      for (int nt = 0; nt < 4; ++nt)
        acc[mt][nt] = __builtin_amdgcn_mfma_f32_16x16x32_bf16(af[mt], bfr[nt], acc[mt][nt], 0, 0, 0);
    __syncthreads();
  }
#pragma unroll
  for (int mt = 0; mt < 4; ++mt)
#pragma unroll
    for (int nt = 0; nt < 4; ++nt)
#pragma unroll
      for (int r = 0; r < 4; ++r) {
        int m = bm + mh * 64 + mt * 16 + kq * 4 + r;
        int n = bn + nh * 64 + nt * 16 + lrow;
        C[(u64)m * ldc + n] = f2b(clampf(acc[mt][nt][r], 60.f));
      }
}

// ---------------------------------------------------------------------------
__global__ __launch_bounds__(256) void part1_kernel(
    const u16* __restrict__ h1sT, const u16* __restrict__ W1c,
    const float* __restrict__ b1c, float* __restrict__ part1)
{
  __shared__ float hN[512];
  const int b = blockIdx.x;
  const int l = threadIdx.x;
  for (int i = l; i < 512; i += 256)
    hN[i] = b2f(h1sT[(u64)1023 * 32768 + (i >> 3) * 512 + b * 8 + (i & 7)]);
  __syncthreads();
  const u16* wrow = W1c + (u64)l * 1024;
  float acc = b1c[l];
  for (int k = 0; k < 512; ++k) acc += hN[k] * b2f(wrow[k]);
  part1[b * 256 + l] = clampf(acc, 60.f);
}

// ---------------------------------------------------------------------------
__global__ __launch_bounds__(256) void escore_kernel(
    const float* __restrict__ part1, const u16* __restrict__ part2,
    const float* __restrict__ W2c, const float* __restrict__ b2c,
    float* __restrict__ e)
{
  const int m = blockIdx.x * 4 + (threadIdx.x >> 6);
  const int lane = threadIdx.x & 63;
  const int b = m & 63, s = m >> 6;
  float acc = 0.f;
  for (int l = lane; l < 256; l += 64)
    acc += tanhfast(part1[b * 256 + l] + b2f(part2[(u64)m * 256 + l])) * W2c[l];
#pragma unroll
  for (int off = 32; off; off >>= 1) acc += __shfl_down(acc, off, 64);
  if (lane == 0) e[b * 1024 + s] = clampf(acc + b2c[0], 60.f);
}

// ---------------------------------------------------------------------------
__global__ __launch_bounds__(256) void finish_kernel(
    const float* __restrict__ e, const u16* __restrict__ h1sT,
    const float* __restrict__ Wfc, const float* __restrict__ bfc,
    void* __restrict__ dout, const u32* __restrict__ flag)
{
  __shared__ float sw[1024];
  __shared__ float red[4];
  __shared__ float hN[512];
  const u32 isf32 = flag[0];
  const int b = blockIdx.x;
  const int tid = threadIdx.x;
  const int lane = tid & 63, wv = tid >> 6;

  float mx = -1e30f;
  for (int s = tid; s < 1024; s += 256) {
    float v = e[b * 1024 + s];
    sw[s] = v;
    mx = fmaxf(mx, v);
  }
#pragma unroll
  for (int off = 1; off < 64; off <<= 1) mx = fmaxf(mx, __shfl_xor(mx, off, 64));
  if (lane == 0) red[wv] = mx;
  __syncthreads();
  mx = fmaxf(fmaxf(red[0], red[1]), fmaxf(red[2], red[3]));
  __syncthreads();

  float sum = 0.f;
  for (int s = tid; s < 1024; s += 256) {
    float p = __expf(sw[s] - mx);
    sw[s] = p;
    sum += p;
  }
#pragma unroll
  for (int off = 1; off < 64; off <<= 1) sum += __shfl_xor(sum, off, 64);
  if (lane == 0) red[wv] = sum;
  __syncthreads();
  sum = red[0] + red[1] + red[2] + red[3];
  float inv = 1.f / sum;
  for (int s = tid; s < 1024; s += 256) {
    float wn = sw[s] * inv;
    sw[s] = wn;
    if (isf32) ((float*)dout)[b * 1024 + s] = wn;
    else       ((u16*)dout)[b * 1024 + s] = f2b(wn);
  }
  for (int i = tid; i < 512; i += 256)
    hN[i] = b2f(h1sT[(u64)1023 * 32768 + (i >> 3) * 512 + b * 8 + (i & 7)]);
  __syncthreads();

  const int c0 = tid, c1 = tid + 256;
  const u64 off0 = (u64)(c0 >> 3) * 512 + b * 8 + (c0 & 7);
  const u64 off1 = (u64)(c1 >> 3) * 512 + b * 8 + (c1 & 7);
  float a0 = 0.f, a1 = 0.f;
  for (int s = 0; s < 1024; ++s) {
    const u16* hr = h1sT + (u64)s * 32768;
    float wn = sw[s];
    a0 += wn * b2f(hr[off0]);
    a1 += wn * b2f(hr[off1]);
  }
  float part = a0 * Wfc[c0] + a1 * Wfc[c1] + hN[c0] * Wfc[512 + c0] + hN[c1] * Wfc[512 + c1];
#pragma unroll
  for (int off = 1; off < 64; off <<= 1) part += __shfl_xor(part, off, 64);
  __syncthreads();
  if (lane == 0) red[wv] = part;
  __syncthreads();
  if (tid == 0) {
    float tot = clampf(red[0] + red[1] + red[2] + red[3] + bfc[0], 30.f);
    float o = sigf(tot);
    if (isf32) ((float*)dout)[65536 + b] = o;
    else       ((u16*)dout)[65536 + b] = f2b(o);
  }
}

// ---------------------------------------------------------------------------
extern "C" void kernel_launch(void* const* d_in, const int* in_sizes, int n_in,
                              void* d_out, int out_size, void* d_ws, size_t ws_size,
                              hipStream_t stream) {
  const int* x_index = (const int*)d_in[0];
  const void* embed = d_in[1];
  const void* Wih0 = d_in[2];
  const void* Whh0 = d_in[3];
  const void* bih0 = d_in[4];
  const void* bhh0 = d_in[5];
  const void* Wih1 = d_in[6];
  const void* Whh1 = d_in[7];
  const void* bih1 = d_in[8];
  const void* bhh1 = d_in[9];
  const void* W1 = d_in[10];
  const void* b1 = d_in[11];
  const void* W2 = d_in[12];
  const void* b2 = d_in[13];
  const void* Wf = d_in[14];
  const void* bfv = d_in[15];

  char* ws = (char*)d_ws;
  size_t off = 0;
  auto alloc = [&](size_t bytes) -> char* {
    char* p = ws + off;
    off += (bytes + 255) & ~(size_t)255;
    return p;
  };
  u32* flags0    = (u32*)alloc(64 * 16 * 4);   // one flag per 64B line
  u32* flags1    = (u32*)alloc(64 * 16 * 4);
  u32* flag      = (u32*)alloc(256);
  float* biasR0  = (float*)alloc(2048 * 4);
  float* biasR1  = (float*)alloc(2048 * 4);
  float* part1   = (float*)alloc(64 * 256 * 4);
  float* e       = (float*)alloc(64 * 1024 * 4);
  float* b1c     = (float*)alloc(256 * 4);
  float* W2c     = (float*)alloc(256 * 4);
  float* b2c     = (float*)alloc(16);
  float* Wfc     = (float*)alloc(1024 * 4);
  float* bfc     = (float*)alloc(16);
  u16* W1c       = (u16*)alloc((size_t)256 * 1024 * 2);
  u16* Wcat0     = (u16*)alloc((size_t)2048 * 832 * 2);
  u16* Wcat1     = (u16*)alloc((size_t)2048 * 1024 * 2);
  u16* xT        = (u16*)alloc((size_t)65536 * 320 * 2);
  u16* h0sT      = (u16*)alloc((size_t)65536 * 512 * 2);
  u16* h1sT      = (u16*)alloc((size_t)65536 * 512 * 2);
  u16* part2     = (u16*)alloc((size_t)65536 * 256 * 2);
  (void)ws_size; (void)in_sizes; (void)n_in; (void)out_size;

  hipMemsetAsync(flags0, 0, 64 * 16 * 4 * 2, stream);  // flags0 + flags1
  hipLaunchKernelGGL(detect_kernel, dim3(1), dim3(256), 0, stream,
                     (const u16*)bih0, flag);
  hipLaunchKernelGGL(prep_kernel, dim3(512), dim3(256), 0, stream,
                     Wih0, Whh0, bih0, bhh0, Wih1, Whh1, bih1, bhh1,
                     W1, b1, W2, b2, Wf, bfv,
                     Wcat0, Wcat1, biasR0, biasR1,
                     W1c, b1c, W2c, b2c, Wfc, bfc, flag);
  hipLaunchKernelGGL(gather_kernel, dim3(16384), dim3(256), 0, stream,
                     x_index, embed, xT, flag);
  hipLaunchKernelGGL(lstm_fused, dim3(128), dim3(256), 0, stream,
                     xT, Wcat0, biasR0, Wcat1, biasR1,
                     h0sT, h1sT, flags0, flags1, 1024);
  hipLaunchKernelGGL(part1_kernel, dim3(64), dim3(256), 0, stream,
                     h1sT, W1c, b1c, part1);
  hipLaunchKernelGGL(gemm_hA, dim3(2, 512), dim3(256), 0, stream,
                     h1sT, W1c + 512, 1024, part2, 256, 512);
  hipLaunchKernelGGL(escore_kernel, dim3(16384), dim3(256), 0, stream,
                     part1, part2, W2c, b2c, e);
  hipLaunchKernelGGL(finish_kernel, dim3(64), dim3(256), 0, stream,
                     e, h1sT, Wfc, bfc, d_out, flag);
}

// Round 8
// 4653.283 us; speedup vs baseline: 1.7849x; 1.1953x over previous
//
#include <hip/hip_runtime.h>

typedef unsigned short u16;
typedef unsigned int u32;
typedef unsigned long long u64;
typedef __attribute__((ext_vector_type(8))) short bf16x8;
typedef __attribute__((ext_vector_type(4))) float f32x4;

__device__ __forceinline__ float b2f(u16 x) {
  union { u32 u; float f; } c; c.u = ((u32)x) << 16; return c.f;
}
__device__ __forceinline__ u16 f2b(float f) {
  union { float f; u32 u; } c; c.f = f;
  u32 u = c.u;
  return (u16)((u + 0x7FFFu + ((u >> 16) & 1u)) >> 16);
}
__device__ __forceinline__ float sigf(float x) { return 1.f / (1.f + __expf(-x)); }
__device__ __forceinline__ float tanhfast(float x) {
  float e = __expf(2.f * x);
  return 1.f - 2.f / (e + 1.f);
}
__device__ __forceinline__ float clampf(float x, float b) {
  return fminf(fmaxf(x, -b), b);
}
__device__ __forceinline__ float loadin(const void* p, long i, u32 isf32) {
  return isf32 ? ((const float*)p)[i] : b2f(((const u16*)p)[i]);
}
// L2-bypassing coherent read (straight from coherence point)
__device__ __forceinline__ u32 l3_load(const u32* p) {
  u32 v;
  asm volatile("global_load_dword %0, %1, off sc0 sc1\n\ts_waitcnt vmcnt(0)"
               : "=v"(v) : "v"(p) : "memory");
  return v;
}
// Write-through store (never lingers dirty in local L2)
__device__ __forceinline__ void l3_store(u32* p, u32 v) {
  asm volatile("global_store_dword %0, %1, off sc0 sc1" :: "v"(p), "v"(v) : "memory");
}
__device__ __forceinline__ void vm_drain() {
  asm volatile("s_waitcnt vmcnt(0)" ::: "memory");
}
// Issue one 16B global load WITHOUT a wait. The asm def cannot be folded into
// the consumer stream or rematerialized -> the batch of issues stays a batch.
// The ONLY drain used is vmcnt(0) (spill-safe: nothing consumes an asm-defined
// register before the full drain, and vmcnt(0) covers any compiler spills).
__device__ __forceinline__ void gload16(bf16x8& d, const u16* p) {
  asm volatile("global_load_dwordx4 %0, %1, off" : "=v"(d) : "v"(p));
}

// Layouts:
//  hsT[t][w8][b][j]  u16 idx = t*32768 + w8*512 + b*8 + j   (w8=64 col-octets)
//  xT [s][k8][b][j]  u16 idx = s*20480 + k8*512 + b*8 + j   (k8=40 col-octets)
// A-fragment of lane (lrow,kq) in wave wv for k-step ks is the contiguous 16B
// at u16 idx (ks*4+kq)*512 + (wv*16+lrow)*8 -> loaded DIRECTLY to registers.
// (LDS staging of A provided zero cross-wave sharing: each wave re-read only
// the bytes it staged. Removing it kills 2 barriers + a full LDS round trip
// + its bank conflicts per phase.)

// ---------------------------------------------------------------------------
__global__ __launch_bounds__(256) void detect_kernel(const u16* __restrict__ bih0,
                                                     u32* __restrict__ flag) {
  __shared__ u32 cnts[2];
  if (threadIdx.x < 2) cnts[threadIdx.x] = 0;
  __syncthreads();
  u32 huge = 0, zeros = 0;
  for (int i = threadIdx.x; i < 2048; i += 256) {
    u16 v = bih0[i];
    u32 e = (v >> 7) & 0xFFu;
    if (e >= 0xC0u) huge++;
    if (v == 0) zeros++;
  }
  atomicAdd(&cnts[0], huge);
  atomicAdd(&cnts[1], zeros);
  __syncthreads();
  if (threadIdx.x == 0) flag[0] = (cnts[0] >= 8u || cnts[1] >= 600u) ? 1u : 0u;
}

// ---------------------------------------------------------------------------
__global__ __launch_bounds__(256) void prep_kernel(
    const void* __restrict__ Wih0, const void* __restrict__ Whh0,
    const void* __restrict__ bih0, const void* __restrict__ bhh0,
    const void* __restrict__ Wih1, const void* __restrict__ Whh1,
    const void* __restrict__ bih1, const void* __restrict__ bhh1,
    const void* __restrict__ W1, const void* __restrict__ b1,
    const void* __restrict__ W2, const void* __restrict__ b2,
    const void* __restrict__ Wf, const void* __restrict__ bfv,
    u16* __restrict__ Wcat0, u16* __restrict__ Wcat1,
    float* __restrict__ biasR0, float* __restrict__ biasR1,
    u16* __restrict__ W1c, float* __restrict__ b1c,
    float* __restrict__ W2c, float* __restrict__ b2c,
    float* __restrict__ Wfc, float* __restrict__ bfc,
    const u32* __restrict__ flag)
{
  const u32 isf32 = flag[0];
  const int gid = blockIdx.x * 256 + threadIdx.x;
  const int gsz = gridDim.x * 256;
  for (int i = gid; i < 2048 * 832; i += gsz) {
    int np = i / 832, k = i - np * 832;
    int g = np & 3, j = np >> 2;
    long orig = g * 512 + j;
    u16 v;
    if (k < 320) v = (k < 300) ? f2b(loadin(Wih0, orig * 300 + k, isf32)) : (u16)0;
    else         v = f2b(loadin(Whh0, orig * 512 + (k - 320), isf32));
    Wcat0[i] = v;
  }
  for (int i = gid; i < 2048 * 1024; i += gsz) {
    int np = i >> 10, k = i & 1023;
    int g = np & 3, j = np >> 2;
    long orig = g * 512 + j;
    Wcat1[i] = (k < 512) ? f2b(loadin(Wih1, orig * 512 + k, isf32))
                         : f2b(loadin(Whh1, orig * 512 + (k - 512), isf32));
  }
  for (int i = gid; i < 2048; i += gsz) {
    int g = i & 3, j = i >> 2;
    long orig = g * 512 + j;
    biasR0[i] = loadin(bih0, orig, isf32) + loadin(bhh0, orig, isf32);
    biasR1[i] = loadin(bih1, orig, isf32) + loadin(bhh1, orig, isf32);
  }
  for (int i = gid; i < 256 * 1024; i += gsz) W1c[i] = f2b(loadin(W1, i, isf32));
  for (int i = gid; i < 256; i += gsz) {
    b1c[i] = loadin(b1, i, isf32);
    W2c[i] = loadin(W2, i, isf32);
  }
  for (int i = gid; i < 1024; i += gsz) Wfc[i] = loadin(Wf, i, isf32);
  if (gid == 0) {
    b2c[0] = loadin(b2, 0, isf32);
    bfc[0] = loadin(bfv, 0, isf32);
  }
}

// ---------------------------------------------------------------------------
// gather -> xT layout: xT[s][c>>3][b][c&7]
// ---------------------------------------------------------------------------
__global__ __launch_bounds__(256) void gather_kernel(
    const int* __restrict__ xi, const void* __restrict__ embed,
    u16* __restrict__ xT, const u32* __restrict__ flag)
{
  const u32 isf32 = flag[0];
  const int r = blockIdx.x * 4 + (threadIdx.x >> 6);
  const int lane = threadIdx.x & 63;
  const int b = r & 63, s = r >> 6;
  const int idx = xi[b * 1024 + s];
  u16* dst = xT + (u64)s * 20480 + b * 8;
  if (!isf32) {
    const u16* src = (const u16*)embed + (u64)idx * 300;
    for (int c = lane; c < 300; c += 64) dst[(c >> 3) * 512 + (c & 7)] = src[c];
  } else {
    const float* src = (const float*)embed + (u64)idx * 300;
    for (int c = lane; c < 300; c += 64) dst[(c >> 3) * 512 + (c & 7)] = f2b(src[c]);
  }
  for (int c = 300 + lane; c < 320; c += 64) dst[(c >> 3) * 512 + (c & 7)] = 0;
}

// ---------------------------------------------------------------------------
// Fused persistent 2-layer LSTM. 128 WGs: 0-63 layer0, 64-127 layer1.
// R7 skeleton (batch-split waves, full-K per wave, weights in LDS, 64 flag
// lines, late own-wait) with the A-tile LDS round trip DELETED:
//  - each lane asm-issues its own A-fragments (batch issue, unfoldable)
//  - x-fragment issue sits before the own-layer poll (latency overlaps it)
//  - ONE vmcnt(0) drain before the MFMA phases; no counted waits anywhere
//  - MFMA loops have compile-time bounds per layer (register-array indexing
//    must be static or it spills to scratch)
// 3 barriers/step (poll release, z exchange, store drain). c-state in regs.
// ---------------------------------------------------------------------------
__global__ __launch_bounds__(256, 1) void lstm_fused(
    const u16* __restrict__ xT,
    const u16* __restrict__ Wcat0, const float* __restrict__ biasR0,
    const u16* __restrict__ Wcat1, const float* __restrict__ biasR1,
    u16* __restrict__ h0sT, u16* __restrict__ h1sT,
    u32* __restrict__ flags0, u32* __restrict__ flags1, int S)
{
  __shared__ __align__(16) u16 ldsW[32 * 1032];   // weight slice, padded pitch
  __shared__ float ldsZ[64 * 33];

  const int layer = blockIdx.x >> 6;
  const int w = blockIdx.x & 63;
  const int KX = layer ? 512 : 320;
  const u16* Wcat = layer ? Wcat1 : Wcat0;
  const float* biasR = layer ? biasR1 : biasR0;
  u16* hs = layer ? h1sT : h0sT;
  u32* fown = layer ? flags1 : flags0;

  const int tid = threadIdx.x;
  const int lane = tid & 63;
  const int wv = tid >> 6;
  const int Kt = KX + 512;
  const int PW = Kt + 8;
  const int nu32 = Kt >> 1;

  {   // weight slice rows w*32..w*32+31 -> LDS (one-time)
    const u32* src = (const u32*)Wcat;
    u32* dst = (u32*)ldsW;
    const int pw2 = PW >> 1;
    for (int i = tid; i < 32 * nu32; i += 256) {
      int r = i / nu32, c = i - r * nu32;
      dst[r * pw2 + c] = src[(u64)(w * 32 + r) * nu32 + c];
    }
  }
  __syncthreads();

  const int lrow = lane & 15;
  const int kq = lane >> 4;
  // u16 offset of this lane's A-fragment within a tile, for k-step ks:
  //   (ks*4 + kq)*512 + (wv*16 + lrow)*8  =  afrag + ks*2048
  const u64 afrag = (u64)kq * 512 + (u64)(wv * 16 + lrow) * 8;
  const int gb = tid >> 2;                  // gates: batch row
  const int gj0 = (tid & 3) * 2;            // gates: first h-col pair
  float c0 = 0.f, c1 = 0.f;                 // c-state, register-resident

  for (int t = 0; t < S; ++t) {
    f32x4 acc0 = {0.f, 0.f, 0.f, 0.f};
    f32x4 acc1 = {0.f, 0.f, 0.f, 0.f};
    bf16x8 ax[16], ah[16];

    // ---- issue projection A-frags as soon as their dependency clears
    if (layer == 0) {
      const u16* xp = xT + (u64)t * 20480 + afrag;   // static input
#pragma unroll
      for (int i = 0; i < 10; ++i) gload16(ax[i], xp + (u64)i * 2048);
      if (t > 0) {
        if (wv == 0) {
          const u32* fp = flags0 + lane * 16;
          const u32 tgt = (u32)t;
          while (!__all((int)(l3_load(fp) >= tgt))) __builtin_amdgcn_s_sleep(1);
        }
        __syncthreads();
      }
    } else {
      if (wv == 0) {   // cross wait: L0 free-runs ahead -> usually first-hit
        const u32* fp = flags0 + lane * 16;
        const u32 tgt = (u32)(t + 1);
        while (!__all((int)(l3_load(fp) >= tgt))) __builtin_amdgcn_s_sleep(1);
      }
      __syncthreads();
      const u16* xp = h0sT + (u64)t * 32768 + afrag;
#pragma unroll
      for (int i = 0; i < 16; ++i) gload16(ax[i], xp + (u64)i * 2048);
      if (t > 0) {     // own wait AFTER x issue: x latency overlaps it
        if (wv == 0) {
          const u32* fp = flags1 + lane * 16;
          const u32 tgt = (u32)t;
          while (!__all((int)(l3_load(fp) >= tgt))) __builtin_amdgcn_s_sleep(1);
        }
        __syncthreads();
      }
    }

    // ---- issue recurrent A-frags, then ONE full drain
    if (t > 0) {
      const u16* hp = hs + (u64)(t - 1) * 32768 + afrag;
#pragma unroll
      for (int i = 0; i < 16; ++i) gload16(ah[i], hp + (u64)i * 2048);
    }
    vm_drain();

    // ---- projection MFMAs (A from registers, B from LDS)
    if (layer == 0) {
#pragma unroll
      for (int ks = 0; ks < 10; ++ks) {
        int k = ks * 32 + kq * 8;
        bf16x8 b0 = *(const bf16x8*)&ldsW[lrow * PW + k];
        bf16x8 b1 = *(const bf16x8*)&ldsW[(16 + lrow) * PW + k];
        acc0 = __builtin_amdgcn_mfma_f32_16x16x32_bf16(ax[ks], b0, acc0, 0, 0, 0);
        acc1 = __builtin_amdgcn_mfma_f32_16x16x32_bf16(ax[ks], b1, acc1, 0, 0, 0);
      }
    } else {
#pragma unroll
      for (int ks = 0; ks < 16; ++ks) {
        int k = ks * 32 + kq * 8;
        bf16x8 b0 = *(const bf16x8*)&ldsW[lrow * PW + k];
        bf16x8 b1 = *(const bf16x8*)&ldsW[(16 + lrow) * PW + k];
        acc0 = __builtin_amdgcn_mfma_f32_16x16x32_bf16(ax[ks], b0, acc0, 0, 0, 0);
        acc1 = __builtin_amdgcn_mfma_f32_16x16x32_bf16(ax[ks], b1, acc1, 0, 0, 0);
      }
    }
    // ---- recurrent MFMAs
    if (t > 0) {
#pragma unroll
      for (int ks = 0; ks < 16; ++ks) {
        int k = KX + ks * 32 + kq * 8;
        bf16x8 b0 = *(const bf16x8*)&ldsW[lrow * PW + k];
        bf16x8 b1 = *(const bf16x8*)&ldsW[(16 + lrow) * PW + k];
        acc0 = __builtin_amdgcn_mfma_f32_16x16x32_bf16(ah[ks], b0, acc0, 0, 0, 0);
        acc1 = __builtin_amdgcn_mfma_f32_16x16x32_bf16(ah[ks], b1, acc1, 0, 0, 0);
      }
    }

    // ---- z tile -> LDS (C layout: col=lane&15, row=quad*4+reg)
    {
      int col = lane & 15, q = lane >> 4;
#pragma unroll
      for (int r = 0; r < 4; ++r) {
        int m = wv * 16 + q * 4 + r;
        ldsZ[m * 33 + col] = acc0[r];
        ldsZ[m * 33 + 16 + col] = acc1[r];
      }
    }
    __syncthreads();

    // ---- gates + contiguous full-line h store (c-state in registers)
    {
      float hv[2];
#pragma unroll
      for (int q2 = 0; q2 < 2; ++q2) {
        int cb = (gj0 + q2) * 4;
        float zi = clampf(ldsZ[gb * 33 + cb + 0] + biasR[w * 32 + cb + 0], 30.f);
        float zf = clampf(ldsZ[gb * 33 + cb + 1] + biasR[w * 32 + cb + 1], 30.f);
        float zg = clampf(ldsZ[gb * 33 + cb + 2] + biasR[w * 32 + cb + 2], 30.f);
        float zo = clampf(ldsZ[gb * 33 + cb + 3] + biasR[w * 32 + cb + 3], 30.f);
        float co = q2 ? c1 : c0;
        float cn = clampf(sigf(zf) * co + sigf(zi) * tanhfast(zg), 64.f);
        if (q2) c1 = cn; else c0 = cn;
        hv[q2] = clampf(sigf(zo) * tanhfast(cn), 1.f);
      }
      u32 packed = (u32)f2b(hv[0]) | ((u32)f2b(hv[1]) << 16);
      l3_store((u32*)hs + (u64)t * 16384 + w * 256 + tid, packed);
      vm_drain();
    }
    __syncthreads();            // all threads' h stores at coherence point
    if (tid == 0) l3_store(fown + w * 16, (u32)(t + 1));
  }
}

// ---------------------------------------------------------------------------
// gemm over hsT A: C[M=65536,N=256](bf16) = A_hsT @ B[N,K=512]^T. 128x128.
// ---------------------------------------------------------------------------
__global__ __launch_bounds__(256, 1) void gemm_hA(
    const u16* __restrict__ A,
    const u16* __restrict__ B, int ldb,
    u16* __restrict__ C, int ldc, int K)
{
  __shared__ __align__(16) u16 As[128 * 40];
  __shared__ __align__(16) u16 Bs[128 * 40];
  const int tid = threadIdx.x;
  const int bn = blockIdx.x * 128;
  const int bm = blockIdx.y * 128;
  const int lane = tid & 63;
  const int wv = tid >> 6;
  const int mh = wv >> 1, nh = wv & 1;
  const int lrow = lane & 15, kq = lane >> 4;
  const int sr = tid >> 1, sh = (tid & 1) * 16;
  const int m_ = bm + sr, s_ = m_ >> 6, bb = m_ & 63;
  f32x4 acc[4][4];
#pragma unroll
  for (int i = 0; i < 4; ++i)
#pragma unroll
    for (int j = 0; j < 4; ++j) acc[i][j] = {0.f, 0.f, 0.f, 0.f};

  for (int k0 = 0; k0 < K; k0 += 32) {
    const u16* ap = A + (u64)s_ * 32768 + (u64)((k0 + sh) >> 3) * 512 + bb * 8;
    *(bf16x8*)&As[sr * 40 + sh]     = *(const bf16x8*)ap;
    *(bf16x8*)&As[sr * 40 + sh + 8] = *(const bf16x8*)(ap + 512);
    *(bf16x8*)&Bs[sr * 40 + sh]     = *(const bf16x8*)(B + (u64)(bn + sr) * ldb + k0 + sh);
    *(bf16x8*)&Bs[sr * 40 + sh + 8] = *(const bf16x8*)(B + (u64)(bn + sr) * ldb + k0 + sh + 8);
    __syncthreads();
    bf16x8 af[4], bfr[4];
#pragma unroll
    for (int mt = 0; mt < 4; ++mt)
      af[mt] = *(const bf16x8*)&As[(mh * 64 + mt * 16 + lrow) * 40 + kq * 8];
#pragma unroll
    for (int nt = 0; nt < 4; ++nt)
      bfr[nt] = *(const bf16x8*)&Bs[(nh * 64 + nt * 16 + lrow) * 40 + kq * 8];
#pragma unroll
    for (int mt = 0; mt < 4; ++mt)
#pragma unroll
      for (int nt = 0; nt < 4; ++nt)
        acc[mt][nt] = __builtin_amdgcn_mfma_f32_16x16x32_bf16(af[mt], bfr[nt], acc[mt][nt], 0, 0, 0);
    __syncthreads();
  }
#pragma unroll
  for (int mt = 0; mt < 4; ++mt)
#pragma unroll
    for (int nt = 0; nt < 4; ++nt)
#pragma unroll
      for (int r = 0; r < 4; ++r) {
        int m = bm + mh * 64 + mt * 16 + kq * 4 + r;
        int n = bn + nh * 64 + nt * 16 + lrow;
        C[(u64)m * ldc + n] = f2b(clampf(acc[mt][nt][r], 60.f));
      }
}

// ---------------------------------------------------------------------------
__global__ __launch_bounds__(256) void part1_kernel(
    const u16* __restrict__ h1sT, const u16* __restrict__ W1c,
    const float* __restrict__ b1c, float* __restrict__ part1)
{
  __shared__ float hN[512];
  const int b = blockIdx.x;
  const int l = threadIdx.x;
  for (int i = l; i < 512; i += 256)
    hN[i] = b2f(h1sT[(u64)1023 * 32768 + (i >> 3) * 512 + b * 8 + (i & 7)]);
  __syncthreads();
  const u16* wrow = W1c + (u64)l * 1024;
  float acc = b1c[l];
  for (int k = 0; k < 512; ++k) acc += hN[k] * b2f(wrow[k]);
  part1[b * 256 + l] = clampf(acc, 60.f);
}

// ---------------------------------------------------------------------------
__global__ __launch_bounds__(256) void escore_kernel(
    const float* __restrict__ part1, const u16* __restrict__ part2,
    const float* __restrict__ W2c, const float* __restrict__ b2c,
    float* __restrict__ e)
{
  const int m = blockIdx.x * 4 + (threadIdx.x >> 6);
  const int lane = threadIdx.x & 63;
  const int b = m & 63, s = m >> 6;
  float acc = 0.f;
  for (int l = lane; l < 256; l += 64)
    acc += tanhfast(part1[b * 256 + l] + b2f(part2[(u64)m * 256 + l])) * W2c[l];
#pragma unroll
  for (int off = 32; off; off >>= 1) acc += __shfl_down(acc, off, 64);
  if (lane == 0) e[b * 1024 + s] = clampf(acc + b2c[0], 60.f);
}

// ---------------------------------------------------------------------------
__global__ __launch_bounds__(256) void finish_kernel(
    const float* __restrict__ e, const u16* __restrict__ h1sT,
    const float* __restrict__ Wfc, const float* __restrict__ bfc,
    void* __restrict__ dout, const u32* __restrict__ flag)
{
  __shared__ float sw[1024];
  __shared__ float red[4];
  __shared__ float hN[512];
  const u32 isf32 = flag[0];
  const int b = blockIdx.x;
  const int tid = threadIdx.x;
  const int lane = tid & 63, wv = tid >> 6;

  float mx = -1e30f;
  for (int s = tid; s < 1024; s += 256) {
    float v = e[b * 1024 + s];
    sw[s] = v;
    mx = fmaxf(mx, v);
  }
#pragma unroll
  for (int off = 1; off < 64; off <<= 1) mx = fmaxf(mx, __shfl_xor(mx, off, 64));
  if (lane == 0) red[wv] = mx;
  __syncthreads();
  mx = fmaxf(fmaxf(red[0], red[1]), fmaxf(red[2], red[3]));
  __syncthreads();

  float sum = 0.f;
  for (int s = tid; s < 1024; s += 256) {
    float p = __expf(sw[s] - mx);
    sw[s] = p;
    sum += p;
  }
#pragma unroll
  for (int off = 1; off < 64; off <<= 1) sum += __shfl_xor(sum, off, 64);
  if (lane == 0) red[wv] = sum;
  __syncthreads();
  sum = red[0] + red[1] + red[2] + red[3];
  float inv = 1.f / sum;
  for (int s = tid; s < 1024; s += 256) {
    float wn = sw[s] * inv;
    sw[s] = wn;
    if (isf32) ((float*)dout)[b * 1024 + s] = wn;
    else       ((u16*)dout)[b * 1024 + s] = f2b(wn);
  }
  for (int i = tid; i < 512; i += 256)
    hN[i] = b2f(h1sT[(u64)1023 * 32768 + (i >> 3) * 512 + b * 8 + (i & 7)]);
  __syncthreads();

  const int c0 = tid, c1 = tid + 256;
  const u64 off0 = (u64)(c0 >> 3) * 512 + b * 8 + (c0 & 7);
  const u64 off1 = (u64)(c1 >> 3) * 512 + b * 8 + (c1 & 7);
  float a0 = 0.f, a1 = 0.f;
  for (int s = 0; s < 1024; ++s) {
    const u16* hr = h1sT + (u64)s * 32768;
    float wn = sw[s];
    a0 += wn * b2f(hr[off0]);
    a1 += wn * b2f(hr[off1]);
  }
  float part = a0 * Wfc[c0] + a1 * Wfc[c1] + hN[c0] * Wfc[512 + c0] + hN[c1] * Wfc[512 + c1];
#pragma unroll
  for (int off = 1; off < 64; off <<= 1) part += __shfl_xor(part, off, 64);
  __syncthreads();
  if (lane == 0) red[wv] = part;
  __syncthreads();
  if (tid == 0) {
    float tot = clampf(red[0] + red[1] + red[2] + red[3] + bfc[0], 30.f);
    float o = sigf(tot);
    if (isf32) ((float*)dout)[65536 + b] = o;
    else       ((u16*)dout)[65536 + b] = f2b(o);
  }
}

// ---------------------------------------------------------------------------
extern "C" void kernel_launch(void* const* d_in, const int* in_sizes, int n_in,
                              void* d_out, int out_size, void* d_ws, size_t ws_size,
                              hipStream_t stream) {
  const int* x_index = (const int*)d_in[0];
  const void* embed = d_in[1];
  const void* Wih0 = d_in[2];
  const void* Whh0 = d_in[3];
  const void* bih0 = d_in[4];
  const void* bhh0 = d_in[5];
  const void* Wih1 = d_in[6];
  const void* Whh1 = d_in[7];
  const void* bih1 = d_in[8];
  const void* bhh1 = d_in[9];
  const void* W1 = d_in[10];
  const void* b1 = d_in[11];
  const void* W2 = d_in[12];
  const void* b2 = d_in[13];
  const void* Wf = d_in[14];
  const void* bfv = d_in[15];

  char* ws = (char*)d_ws;
  size_t off = 0;
  auto alloc = [&](size_t bytes) -> char* {
    char* p = ws + off;
    off += (bytes + 255) & ~(size_t)255;
    return p;
  };
  u32* flags0    = (u32*)alloc(64 * 16 * 4);   // one flag per 64B line
  u32* flags1    = (u32*)alloc(64 * 16 * 4);
  u32* flag      = (u32*)alloc(256);
  float* biasR0  = (float*)alloc(2048 * 4);
  float* biasR1  = (float*)alloc(2048 * 4);
  float* part1   = (float*)alloc(64 * 256 * 4);
  float* e       = (float*)alloc(64 * 1024 * 4);
  float* b1c     = (float*)alloc(256 * 4);
  float* W2c     = (float*)alloc(256 * 4);
  float* b2c     = (float*)alloc(16);
  float* Wfc     = (float*)alloc(1024 * 4);
  float* bfc     = (float*)alloc(16);
  u16* W1c       = (u16*)alloc((size_t)256 * 1024 * 2);
  u16* Wcat0     = (u16*)alloc((size_t)2048 * 832 * 2);
  u16* Wcat1     = (u16*)alloc((size_t)2048 * 1024 * 2);
  u16* xT        = (u16*)alloc((size_t)65536 * 320 * 2);
  u16* h0sT      = (u16*)alloc((size_t)65536 * 512 * 2);
  u16* h1sT      = (u16*)alloc((size_t)65536 * 512 * 2);
  u16* part2     = (u16*)alloc((size_t)65536 * 256 * 2);
  (void)ws_size; (void)in_sizes; (void)n_in; (void)out_size;

  hipMemsetAsync(flags0, 0, 64 * 16 * 4 * 2, stream);  // flags0 + flags1
  hipLaunchKernelGGL(detect_kernel, dim3(1), dim3(256), 0, stream,
                     (const u16*)bih0, flag);
  hipLaunchKernelGGL(prep_kernel, dim3(512), dim3(256), 0, stream,
                     Wih0, Whh0, bih0, bhh0, Wih1, Whh1, bih1, bhh1,
                     W1, b1, W2, b2, Wf, bfv,
                     Wcat0, Wcat1, biasR0, biasR1,
                     W1c, b1c, W2c, b2c, Wfc, bfc, flag);
  hipLaunchKernelGGL(gather_kernel, dim3(16384), dim3(256), 0, stream,
                     x_index, embed, xT, flag);
  hipLaunchKernelGGL(lstm_fused, dim3(128), dim3(256), 0, stream,
                     xT, Wcat0, biasR0, Wcat1, biasR1,
                     h0sT, h1sT, flags0, flags1, 1024);
  hipLaunchKernelGGL(part1_kernel, dim3(64), dim3(256), 0, stream,
                     h1sT, W1c, b1c, part1);
  hipLaunchKernelGGL(gemm_hA, dim3(2, 512), dim3(256), 0, stream,
                     h1sT, W1c + 512, 1024, part2, 256, 512);
  hipLaunchKernelGGL(escore_kernel, dim3(16384), dim3(256), 0, stream,
                     part1, part2, W2c, b2c, e);
  hipLaunchKernelGGL(finish_kernel, dim3(64), dim3(256), 0, stream,
                     e, h1sT, Wfc, bfc, d_out, flag);
}

// Round 10
// 4177.399 us; speedup vs baseline: 1.9882x; 1.1139x over previous
//
#include <hip/hip_runtime.h>

typedef unsigned short u16;
typedef unsigned int u32;
typedef unsigned long long u64;
typedef __attribute__((ext_vector_type(8))) short bf16x8;
typedef __attribute__((ext_vector_type(4))) float f32x4;
typedef __attribute__((ext_vector_type(16))) float f32x16;

__device__ __forceinline__ float b2f(u16 x) {
  union { u32 u; float f; } c; c.u = ((u32)x) << 16; return c.f;
}
__device__ __forceinline__ u16 f2b(float f) {
  union { float f; u32 u; } c; c.f = f;
  u32 u = c.u;
  return (u16)((u + 0x7FFFu + ((u >> 16) & 1u)) >> 16);
}
__device__ __forceinline__ float sigf(float x) { return 1.f / (1.f + __expf(-x)); }
__device__ __forceinline__ float tanhfast(float x) {
  float e = __expf(2.f * x);
  return 1.f - 2.f / (e + 1.f);
}
__device__ __forceinline__ float clampf(float x, float b) {
  return fminf(fmaxf(x, -b), b);
}
__device__ __forceinline__ float loadin(const void* p, long i, u32 isf32) {
  return isf32 ? ((const float*)p)[i] : b2f(((const u16*)p)[i]);
}
// L2-bypassing coherent read (straight from coherence point)
__device__ __forceinline__ u32 l3_load(const u32* p) {
  u32 v;
  asm volatile("global_load_dword %0, %1, off sc0 sc1\n\ts_waitcnt vmcnt(0)"
               : "=v"(v) : "v"(p) : "memory");
  return v;
}
// Write-through store (never lingers dirty in local L2)
__device__ __forceinline__ void l3_store(u32* p, u32 v) {
  asm volatile("global_store_dword %0, %1, off sc0 sc1" :: "v"(p), "v"(v) : "memory");
}
__device__ __forceinline__ void vm_drain() {
  asm volatile("s_waitcnt vmcnt(0)" ::: "memory");
}
// Full drain + scheduling fence: rule-#18 guard -- register-only MFMAs can be
// hoisted past an inline-asm waitcnt (the "memory" clobber does not order
// register reads). sched_barrier(0) pins everything below the drain.
__device__ __forceinline__ void vm_drain_fenced() {
  asm volatile("s_waitcnt vmcnt(0)" ::: "memory");
  __builtin_amdgcn_sched_barrier(0);
}
// Issue one 16B global load WITHOUT a wait. The asm def cannot be folded,
// rematerialized, or refetched -> batches stay batches, values stay in VGPRs.
__device__ __forceinline__ void gload16(bf16x8& d, const u16* p) {
  asm volatile("global_load_dwordx4 %0, %1, off" : "=v"(d) : "v"(p));
}

// Layouts:
//  hsT[t][w8][b][j]  u16 idx = t*32768 + w8*512 + b*8 + j   (w8=64 col-octets)
//  xT [s][k8][b][j]  u16 idx = s*20480 + k8*512 + b*8 + j   (k8=40 col-octets)
// 32x32x16 MFMA, wave (mh=wv&1, kh=wv>>1): batch rows mh*32..+31, K-half kh.
// Lane l: A row = mh*32 + (l&31), k-octet = l>>5 -> 16B contiguous in global.
// B row (gate) = w*32 + (l&31). A and B direct to registers; z via ldsZ.
// Register budget (the R9 lesson): asm defs can't spill and need aligned
// quads, so only ONE A-phase array (64 VGPRs) is live at a time -- the
// projection and recurrent phases time-share it. Peak ~250 VGPRs.

#define Z16 {0.f,0.f,0.f,0.f,0.f,0.f,0.f,0.f,0.f,0.f,0.f,0.f,0.f,0.f,0.f,0.f}

// write the wave's 32x32 partial-z tile into its K-half ldsZ buffer.
// C layout (32x32x16): col=lane&31, row=(reg&3)+8*(reg>>2)+4*(lane>>5)
__device__ __forceinline__ void zwrite(float* __restrict__ zp,
                                       const f32x16& a, const f32x16& b,
                                       int mh, int l5, int l31) {
#pragma unroll
  for (int r = 0; r < 16; ++r) {
    int row = mh * 32 + (r & 3) + ((r >> 2) << 3) + (l5 << 2);
    zp[row * 33 + l31] = a[r] + b[r];
  }
}

__device__ __forceinline__ void gates_store(const float* __restrict__ ldsZ,
                                            const float* __restrict__ biasR,
                                            int w, int tid, int gb, int gj0, int t,
                                            u16* __restrict__ hs,
                                            float& c0, float& c1) {
  const float* zr0 = ldsZ + gb * 33;
  const float* zr1 = ldsZ + 64 * 33 + gb * 33;
  const float* br = biasR + w * 32;
  float hv[2];
#pragma unroll
  for (int q2 = 0; q2 < 2; ++q2) {
    int cb = (gj0 + q2) * 4;
    float zi = clampf(zr0[cb + 0] + zr1[cb + 0] + br[cb + 0], 30.f);
    float zf = clampf(zr0[cb + 1] + zr1[cb + 1] + br[cb + 1], 30.f);
    float zg = clampf(zr0[cb + 2] + zr1[cb + 2] + br[cb + 2], 30.f);
    float zo = clampf(zr0[cb + 3] + zr1[cb + 3] + br[cb + 3], 30.f);
    float co = q2 ? c1 : c0;
    float cn = clampf(sigf(zf) * co + sigf(zi) * tanhfast(zg), 64.f);
    if (q2) c1 = cn; else c0 = cn;
    hv[q2] = clampf(sigf(zo) * tanhfast(cn), 1.f);
  }
  u32 packed = (u32)f2b(hv[0]) | ((u32)f2b(hv[1]) << 16);
  l3_store((u32*)hs + (u64)t * 16384 + w * 256 + tid, packed);
  vm_drain();
}

// ---------------------------------------------------------------------------
__global__ __launch_bounds__(256) void detect_kernel(const u16* __restrict__ bih0,
                                                     u32* __restrict__ flag) {
  __shared__ u32 cnts[2];
  if (threadIdx.x < 2) cnts[threadIdx.x] = 0;
  __syncthreads();
  u32 huge = 0, zeros = 0;
  for (int i = threadIdx.x; i < 2048; i += 256) {
    u16 v = bih0[i];
    u32 e = (v >> 7) & 0xFFu;
    if (e >= 0xC0u) huge++;
    if (v == 0) zeros++;
  }
  atomicAdd(&cnts[0], huge);
  atomicAdd(&cnts[1], zeros);
  __syncthreads();
  if (threadIdx.x == 0) flag[0] = (cnts[0] >= 8u || cnts[1] >= 600u) ? 1u : 0u;
}

// ---------------------------------------------------------------------------
__global__ __launch_bounds__(256) void prep_kernel(
    const void* __restrict__ Wih0, const void* __restrict__ Whh0,
    const void* __restrict__ bih0, const void* __restrict__ bhh0,
    const void* __restrict__ Wih1, const void* __restrict__ Whh1,
    const void* __restrict__ bih1, const void* __restrict__ bhh1,
    const void* __restrict__ W1, const void* __restrict__ b1,
    const void* __restrict__ W2, const void* __restrict__ b2,
    const void* __restrict__ Wf, const void* __restrict__ bfv,
    u16* __restrict__ Wcat0, u16* __restrict__ Wcat1,
    float* __restrict__ biasR0, float* __restrict__ biasR1,
    u16* __restrict__ W1c, float* __restrict__ b1c,
    float* __restrict__ W2c, float* __restrict__ b2c,
    float* __restrict__ Wfc, float* __restrict__ bfc,
    const u32* __restrict__ flag)
{
  const u32 isf32 = flag[0];
  const int gid = blockIdx.x * 256 + threadIdx.x;
  const int gsz = gridDim.x * 256;
  for (int i = gid; i < 2048 * 832; i += gsz) {
    int np = i / 832, k = i - np * 832;
    int g = np & 3, j = np >> 2;
    long orig = g * 512 + j;
    u16 v;
    if (k < 320) v = (k < 300) ? f2b(loadin(Wih0, orig * 300 + k, isf32)) : (u16)0;
    else         v = f2b(loadin(Whh0, orig * 512 + (k - 320), isf32));
    Wcat0[i] = v;
  }
  for (int i = gid; i < 2048 * 1024; i += gsz) {
    int np = i >> 10, k = i & 1023;
    int g = np & 3, j = np >> 2;
    long orig = g * 512 + j;
    Wcat1[i] = (k < 512) ? f2b(loadin(Wih1, orig * 512 + k, isf32))
                         : f2b(loadin(Whh1, orig * 512 + (k - 512), isf32));
  }
  for (int i = gid; i < 2048; i += gsz) {
    int g = i & 3, j = i >> 2;
    long orig = g * 512 + j;
    biasR0[i] = loadin(bih0, orig, isf32) + loadin(bhh0, orig, isf32);
    biasR1[i] = loadin(bih1, orig, isf32) + loadin(bhh1, orig, isf32);
  }
  for (int i = gid; i < 256 * 1024; i += gsz) W1c[i] = f2b(loadin(W1, i, isf32));
  for (int i = gid; i < 256; i += gsz) {
    b1c[i] = loadin(b1, i, isf32);
    W2c[i] = loadin(W2, i, isf32);
  }
  for (int i = gid; i < 1024; i += gsz) Wfc[i] = loadin(Wf, i, isf32);
  if (gid == 0) {
    b2c[0] = loadin(b2, 0, isf32);
    bfc[0] = loadin(bfv, 0, isf32);
  }
}

// ---------------------------------------------------------------------------
// gather -> xT layout: xT[s][c>>3][b][c&7]
// ---------------------------------------------------------------------------
__global__ __launch_bounds__(256) void gather_kernel(
    const int* __restrict__ xi, const void* __restrict__ embed,
    u16* __restrict__ xT, const u32* __restrict__ flag)
{
  const u32 isf32 = flag[0];
  const int r = blockIdx.x * 4 + (threadIdx.x >> 6);
  const int lane = threadIdx.x & 63;
  const int b = r & 63, s = r >> 6;
  const int idx = xi[b * 1024 + s];
  u16* dst = xT + (u64)s * 20480 + b * 8;
  if (!isf32) {
    const u16* src = (const u16*)embed + (u64)idx * 300;
    for (int c = lane; c < 300; c += 64) dst[(c >> 3) * 512 + (c & 7)] = src[c];
  } else {
    const float* src = (const float*)embed + (u64)idx * 300;
    for (int c = lane; c < 300; c += 64) dst[(c >> 3) * 512 + (c & 7)] = f2b(src[c]);
  }
  for (int c = 300 + lane; c < 320; c += 64) dst[(c >> 3) * 512 + (c & 7)] = 0;
}

// ---------------------------------------------------------------------------
// Fused persistent 2-layer LSTM. 128 WGs: 0-63 layer0, 64-127 layer1.
// Register-operand design (R9) with halved pressure (R10):
//  - B fragments asm-loaded once -> VGPR-resident for the whole sequence
//  - ONE time-shared A array per step: issue x -> drain -> MFMA-x ->
//    issue h (same regs) -> drain -> MFMA-h
//  - sched_barrier(0) after each drain (no MFMA hoisting past the waitcnt)
//  - NO ldsW; LDS = z-exchange only (conflict-free stride 33)
// Sync protocol (64 flag lines, sc0/sc1, late own-wait) unchanged from R8.
// ---------------------------------------------------------------------------
__global__ __launch_bounds__(256, 1) void lstm_fused(
    const u16* __restrict__ xT,
    const u16* __restrict__ Wcat0, const float* __restrict__ biasR0,
    const u16* __restrict__ Wcat1, const float* __restrict__ biasR1,
    u16* __restrict__ h0sT, u16* __restrict__ h1sT,
    u32* __restrict__ flags0, u32* __restrict__ flags1, int S)
{
  __shared__ float ldsZ[2 * 64 * 33];   // K-half partial z tiles (16.9 KB)

  const int layer = blockIdx.x >> 6;
  const int w = blockIdx.x & 63;
  const int tid = threadIdx.x;
  const int lane = tid & 63;
  const int wv = tid >> 6;
  const int mh = wv & 1;      // batch half (rows mh*32..mh*32+31)
  const int kh = wv >> 1;     // K half
  const int l5 = lane >> 5;   // k-octet select within k16 step
  const int l31 = lane & 31;

  const float* biasR = layer ? biasR1 : biasR0;
  u16* hs = layer ? h1sT : h0sT;
  u32* fown = layer ? flags1 : flags0;

  // ---- persistent B fragments: asm-loaded once, VGPR-resident forever
  bf16x8 bx[16], bh[16];
  if (layer == 0) {
    const u16* wr = Wcat0 + (u64)(w * 32 + l31) * 832 + l5 * 8;
#pragma unroll
    for (int i = 0; i < 10; ++i) gload16(bx[i], wr + (kh * 10 + i) * 16);
#pragma unroll
    for (int i = 0; i < 16; ++i) gload16(bh[i], wr + 320 + (kh * 16 + i) * 16);
  } else {
    const u16* wr = Wcat1 + (u64)(w * 32 + l31) * 1024 + l5 * 8;
#pragma unroll
    for (int i = 0; i < 16; ++i) gload16(bx[i], wr + (kh * 16 + i) * 16);
#pragma unroll
    for (int i = 0; i < 16; ++i) gload16(bh[i], wr + 512 + (kh * 16 + i) * 16);
  }
  vm_drain_fenced();

  const u64 abase = (u64)(mh * 32 + l31) * 8;   // A-frag row offset (u16)
  const int gb = tid >> 2;                      // gates: batch row
  const int gj0 = (tid & 3) * 2;                // gates: first h-col (of 8)
  float c0 = 0.f, c1 = 0.f;                     // c-state, register-resident
  float* zp = ldsZ + kh * (64 * 33);

  for (int t = 0; t < S; ++t) {
    f32x16 accA = Z16, accB = Z16;
    bf16x8 a[16];   // time-shared: x-phase then h-phase (64 VGPRs, not 128)

    // ---- issue projection A-frags at their dependency point
    if (layer == 0) {
      const u16* xp = xT + (u64)t * 20480 + (u64)(kh * 20 + l5) * 512 + abase;
#pragma unroll
      for (int i = 0; i < 10; ++i) gload16(a[i], xp + (u64)i * 1024);
      if (t > 0) {
        if (wv == 0) {
          const u32* fp = flags0 + lane * 16;
          const u32 tgt = (u32)t;
          while (!__all((int)(l3_load(fp) >= tgt))) __builtin_amdgcn_s_sleep(1);
        }
        __syncthreads();
      }
    } else {
      if (wv == 0) {   // cross wait: L0 free-runs ahead -> usually first-hit
        const u32* fp = flags0 + lane * 16;
        const u32 tgt = (u32)(t + 1);
        while (!__all((int)(l3_load(fp) >= tgt))) __builtin_amdgcn_s_sleep(1);
      }
      __syncthreads();
      const u16* xp = h0sT + (u64)t * 32768 + (u64)(kh * 32 + l5) * 512 + abase;
#pragma unroll
      for (int i = 0; i < 16; ++i) gload16(a[i], xp + (u64)i * 1024);
      if (t > 0) {     // own wait AFTER x issue: x latency overlaps it
        if (wv == 0) {
          const u32* fp = flags1 + lane * 16;
          const u32 tgt = (u32)t;
          while (!__all((int)(l3_load(fp) >= tgt))) __builtin_amdgcn_s_sleep(1);
        }
        __syncthreads();
      }
    }
    vm_drain_fenced();

    // ---- projection MFMAs (A and B both register-resident)
    if (layer == 0) {
#pragma unroll
      for (int i = 0; i < 10; ++i) {
        if (i & 1) accB = __builtin_amdgcn_mfma_f32_32x32x16_bf16(a[i], bx[i], accB, 0, 0, 0);
        else       accA = __builtin_amdgcn_mfma_f32_32x32x16_bf16(a[i], bx[i], accA, 0, 0, 0);
      }
    } else {
#pragma unroll
      for (int i = 0; i < 16; ++i) {
        if (i & 1) accB = __builtin_amdgcn_mfma_f32_32x32x16_bf16(a[i], bx[i], accB, 0, 0, 0);
        else       accA = __builtin_amdgcn_mfma_f32_32x32x16_bf16(a[i], bx[i], accA, 0, 0, 0);
      }
    }

    // ---- recurrent phase: same registers, new loads
    if (t > 0) {
      const u16* hp = hs + (u64)(t - 1) * 32768 + (u64)(kh * 32 + l5) * 512 + abase;
#pragma unroll
      for (int i = 0; i < 16; ++i) gload16(a[i], hp + (u64)i * 1024);
      vm_drain_fenced();
#pragma unroll
      for (int i = 0; i < 16; ++i) {
        if (i & 1) accB = __builtin_amdgcn_mfma_f32_32x32x16_bf16(a[i], bh[i], accB, 0, 0, 0);
        else       accA = __builtin_amdgcn_mfma_f32_32x32x16_bf16(a[i], bh[i], accA, 0, 0, 0);
      }
    }

    // ---- z-half tiles -> LDS, cross-wave K reduction
    zwrite(zp, accA, accB, mh, l5, l31);
    __syncthreads();
    gates_store(ldsZ, biasR, w, tid, gb, gj0, t, hs, c0, c1);
    __syncthreads();            // all threads' h stores at coherence point
    if (tid == 0) l3_store(fown + w * 16, (u32)(t + 1));
  }
}

// ---------------------------------------------------------------------------
// gemm over hsT A: C[M=65536,N=256](bf16) = A_hsT @ B[N,K=512]^T. 128x128.
// ---------------------------------------------------------------------------
__global__ __launch_bounds__(256, 1) void gemm_hA(
    const u16* __restrict__ A,
    const u16* __restrict__ B, int ldb,
    u16* __restrict__ C, int ldc, int K)
{
  __shared__ __align__(16) u16 As[128 * 40];
  __shared__ __align__(16) u16 Bs[128 * 40];
  const int tid = threadIdx.x;
  const int bn = blockIdx.x * 128;
  const int bm = blockIdx.y * 128;
  const int lane = tid & 63;
  const int wv = tid >> 6;
  const int mh = wv >> 1, nh = wv & 1;
  const int lrow = lane & 15, kq = lane >> 4;
  const int sr = tid >> 1, sh = (tid & 1) * 16;
  const int m_ = bm + sr, s_ = m_ >> 6, bb = m_ & 63;
  f32x4 acc[4][4];
#pragma unroll
  for (int i = 0; i < 4; ++i)
#pragma unroll
    for (int j = 0; j < 4; ++j) acc[i][j] = {0.f, 0.f, 0.f, 0.f};

  for (int k0 = 0; k0 < K; k0 += 32) {
    const u16* ap = A + (u64)s_ * 32768 + (u64)((k0 + sh) >> 3) * 512 + bb * 8;
    *(bf16x8*)&As[sr * 40 + sh]     = *(const bf16x8*)ap;
    *(bf16x8*)&As[sr * 40 + sh + 8] = *(const bf16x8*)(ap + 512);
    *(bf16x8*)&Bs[sr * 40 + sh]     = *(const bf16x8*)(B + (u64)(bn + sr) * ldb + k0 + sh);
    *(bf16x8*)&Bs[sr * 40 + sh + 8] = *(const bf16x8*)(B + (u64)(bn + sr) * ldb + k0 + sh + 8);
    __syncthreads();
    bf16x8 af[4], bfr[4];
#pragma unroll
    for (int mt = 0; mt < 4; ++mt)
      af[mt] = *(const bf16x8*)&As[(mh * 64 + mt * 16 + lrow) * 40 + kq * 8];
#pragma unroll
    for (int nt = 0; nt < 4; ++nt)
      bfr[nt] = *(const bf16x8*)&Bs[(nh * 64 + nt * 16 + lrow) * 40 + kq * 8];
#pragma unroll
    for (int mt = 0; mt < 4; ++mt)
#pragma unroll
      for (int nt = 0; nt < 4; ++nt)
        acc[mt][nt] = __builtin_amdgcn_mfma_f32_16x16x32_bf16(af[mt], bfr[nt], acc[mt][nt], 0, 0, 0);
    __syncthreads();
  }
#pragma unroll
  for (int mt = 0; mt < 4; ++mt)
#pragma unroll
    for (int nt = 0; nt < 4; ++nt)
#pragma unroll
      for (int r = 0; r < 4; ++r) {
        int m = bm + mh * 64 + mt * 16 + kq * 4 + r;
        int n = bn + nh * 64 + nt * 16 + lrow;
        C[(u64)m * ldc + n] = f2b(clampf(acc[mt][nt][r], 60.f));
      }
}

// ---------------------------------------------------------------------------
__global__ __launch_bounds__(256) void part1_kernel(
    const u16* __restrict__ h1sT, const u16* __restrict__ W1c,
    const float* __restrict__ b1c, float* __restrict__ part1)
{
  __shared__ float hN[512];
  const int b = blockIdx.x;
  const int l = threadIdx.x;
  for (int i = l; i < 512; i += 256)
    hN[i] = b2f(h1sT[(u64)1023 * 32768 + (i >> 3) * 512 + b * 8 + (i & 7)]);
  __syncthreads();
  const u16* wrow = W1c + (u64)l * 1024;
  float acc = b1c[l];
  for (int k = 0; k < 512; ++k) acc += hN[k] * b2f(wrow[k]);
  part1[b * 256 + l] = clampf(acc, 60.f);
}

// ---------------------------------------------------------------------------
__global__ __launch_bounds__(256) void escore_kernel(
    const float* __restrict__ part1, const u16* __restrict__ part2,
    const float* __restrict__ W2c, const float* __restrict__ b2c,
    float* __restrict__ e)
{
  const int m = blockIdx.x * 4 + (threadIdx.x >> 6);
  const int lane = threadIdx.x & 63;
  const int b = m & 63, s = m >> 6;
  float acc = 0.f;
  for (int l = lane; l < 256; l += 64)
    acc += tanhfast(part1[b * 256 + l] + b2f(part2[(u64)m * 256 + l])) * W2c[l];
#pragma unroll
  for (int off = 32; off; off >>= 1) acc += __shfl_down(acc, off, 64);
  if (lane == 0) e[b * 1024 + s] = clampf(acc + b2c[0], 60.f);
}

// ---------------------------------------------------------------------------
__global__ __launch_bounds__(256) void finish_kernel(
    const float* __restrict__ e, const u16* __restrict__ h1sT,
    const float* __restrict__ Wfc, const float* __restrict__ bfc,
    void* __restrict__ dout, const u32* __restrict__ flag)
{
  __shared__ float sw[1024];
  __shared__ float red[4];
  __shared__ float hN[512];
  const u32 isf32 = flag[0];
  const int b = blockIdx.x;
  const int tid = threadIdx.x;
  const int lane = tid & 63, wv = tid >> 6;

  float mx = -1e30f;
  for (int s = tid; s < 1024; s += 256) {
    float v = e[b * 1024 + s];
    sw[s] = v;
    mx = fmaxf(mx, v);
  }
#pragma unroll
  for (int off = 1; off < 64; off <<= 1) mx = fmaxf(mx, __shfl_xor(mx, off, 64));
  if (lane == 0) red[wv] = mx;
  __syncthreads();
  mx = fmaxf(fmaxf(red[0], red[1]), fmaxf(red[2], red[3]));
  __syncthreads();

  float sum = 0.f;
  for (int s = tid; s < 1024; s += 256) {
    float p = __expf(sw[s] - mx);
    sw[s] = p;
    sum += p;
  }
#pragma unroll
  for (int off = 1; off < 64; off <<= 1) sum += __shfl_xor(sum, off, 64);
  if (lane == 0) red[wv] = sum;
  __syncthreads();
  sum = red[0] + red[1] + red[2] + red[3];
  float inv = 1.f / sum;
  for (int s = tid; s < 1024; s += 256) {
    float wn = sw[s] * inv;
    sw[s] = wn;
    if (isf32) ((float*)dout)[b * 1024 + s] = wn;
    else       ((u16*)dout)[b * 1024 + s] = f2b(wn);
  }
  for (int i = tid; i < 512; i += 256)
    hN[i] = b2f(h1sT[(u64)1023 * 32768 + (i >> 3) * 512 + b * 8 + (i & 7)]);
  __syncthreads();

  const int c0 = tid, c1 = tid + 256;
  const u64 off0 = (u64)(c0 >> 3) * 512 + b * 8 + (c0 & 7);
  const u64 off1 = (u64)(c1 >> 3) * 512 + b * 8 + (c1 & 7);
  float a0 = 0.f, a1 = 0.f;
  for (int s = 0; s < 1024; ++s) {
    const u16* hr = h1sT + (u64)s * 32768;
    float wn = sw[s];
    a0 += wn * b2f(hr[off0]);
    a1 += wn * b2f(hr[off1]);
  }
  float part = a0 * Wfc[c0] + a1 * Wfc[c1] + hN[c0] * Wfc[512 + c0] + hN[c1] * Wfc[512 + c1];
#pragma unroll
  for (int off = 1; off < 64; off <<= 1) part += __shfl_xor(part, off, 64);
  __syncthreads();
  if (lane == 0) red[wv] = part;
  __syncthreads();
  if (tid == 0) {
    float tot = clampf(red[0] + red[1] + red[2] + red[3] + bfc[0], 30.f);
    float o = sigf(tot);
    if (isf32) ((float*)dout)[65536 + b] = o;
    else       ((u16*)dout)[65536 + b] = f2b(o);
  }
}

// ---------------------------------------------------------------------------
extern "C" void kernel_launch(void* const* d_in, const int* in_sizes, int n_in,
                              void* d_out, int out_size, void* d_ws, size_t ws_size,
                              hipStream_t stream) {
  const int* x_index = (const int*)d_in[0];
  const void* embed = d_in[1];
  const void* Wih0 = d_in[2];
  const void* Whh0 = d_in[3];
  const void* bih0 = d_in[4];
  const void* bhh0 = d_in[5];
  const void* Wih1 = d_in[6];
  const void* Whh1 = d_in[7];
  const void* bih1 = d_in[8];
  const void* bhh1 = d_in[9];
  const void* W1 = d_in[10];
  const void* b1 = d_in[11];
  const void* W2 = d_in[12];
  const void* b2 = d_in[13];
  const void* Wf = d_in[14];
  const void* bfv = d_in[15];

  char* ws = (char*)d_ws;
  size_t off = 0;
  auto alloc = [&](size_t bytes) -> char* {
    char* p = ws + off;
    off += (bytes + 255) & ~(size_t)255;
    return p;
  };
  u32* flags0    = (u32*)alloc(64 * 16 * 4);   // one flag per 64B line
  u32* flags1    = (u32*)alloc(64 * 16 * 4);
  u32* flag      = (u32*)alloc(256);
  float* biasR0  = (float*)alloc(2048 * 4);
  float* biasR1  = (float*)alloc(2048 * 4);
  float* part1   = (float*)alloc(64 * 256 * 4);
  float* e       = (float*)alloc(64 * 1024 * 4);
  float* b1c     = (float*)alloc(256 * 4);
  float* W2c     = (float*)alloc(256 * 4);
  float* b2c     = (float*)alloc(16);
  float* Wfc     = (float*)alloc(1024 * 4);
  float* bfc     = (float*)alloc(16);
  u16* W1c       = (u16*)alloc((size_t)256 * 1024 * 2);
  u16* Wcat0     = (u16*)alloc((size_t)2048 * 832 * 2);
  u16* Wcat1     = (u16*)alloc((size_t)2048 * 1024 * 2);
  u16* xT        = (u16*)alloc((size_t)65536 * 320 * 2);
  u16* h0sT      = (u16*)alloc((size_t)65536 * 512 * 2);
  u16* h1sT      = (u16*)alloc((size_t)65536 * 512 * 2);
  u16* part2     = (u16*)alloc((size_t)65536 * 256 * 2);
  (void)ws_size; (void)in_sizes; (void)n_in; (void)out_size;

  hipMemsetAsync(flags0, 0, 64 * 16 * 4 * 2, stream);  // flags0 + flags1
  hipLaunchKernelGGL(detect_kernel, dim3(1), dim3(256), 0, stream,
                     (const u16*)bih0, flag);
  hipLaunchKernelGGL(prep_kernel, dim3(512), dim3(256), 0, stream,
                     Wih0, Whh0, bih0, bhh0, Wih1, Whh1, bih1, bhh1,
                     W1, b1, W2, b2, Wf, bfv,
                     Wcat0, Wcat1, biasR0, biasR1,
                     W1c, b1c, W2c, b2c, Wfc, bfc, flag);
  hipLaunchKernelGGL(gather_kernel, dim3(16384), dim3(256), 0, stream,
                     x_index, embed, xT, flag);
  hipLaunchKernelGGL(lstm_fused, dim3(128), dim3(256), 0, stream,
                     xT, Wcat0, biasR0, Wcat1, biasR1,
                     h0sT, h1sT, flags0, flags1, 1024);
  hipLaunchKernelGGL(part1_kernel, dim3(64), dim3(256), 0, stream,
                     h1sT, W1c, b1c, part1);
  hipLaunchKernelGGL(gemm_hA, dim3(2, 512), dim3(256), 0, stream,
                     h1sT, W1c + 512, 1024, part2, 256, 512);
  hipLaunchKernelGGL(escore_kernel, dim3(16384), dim3(256), 0, stream,
                     part1, part2, W2c, b2c, e);
  hipLaunchKernelGGL(finish_kernel, dim3(64), dim3(256), 0, stream,
                     e, h1sT, Wfc, bfc, d_out, flag);
}